// Round 9
// baseline (1218.988 us; speedup 1.0000x reference)
//
#include <hip/hip_runtime.h>
#include <cstdint>
#include <cstddef>

// ---------------------------------------------------------------- types/helpers
typedef __attribute__((ext_vector_type(8))) short bfrag8;   // 8 bf16 = 4 VGPR (MFMA A/B frag)
typedef __attribute__((ext_vector_type(4))) float facc4;    // MFMA C/D frag

#define DEV static __device__ __forceinline__

DEV uint16_t f2b(float f){                       // f32 -> bf16, RNE
  uint32_t b = __builtin_bit_cast(uint32_t, f);
  return (uint16_t)((b + 0x7FFFu + ((b >> 16) & 1u)) >> 16);
}
DEV float b2f(uint16_t h){
  uint32_t b = ((uint32_t)h) << 16;
  return __builtin_bit_cast(float, b);
}
DEV void gload_lds16(const void* g, void* l){    // async global->LDS, 16B/lane
  __builtin_amdgcn_global_load_lds((const __attribute__((address_space(1))) unsigned int*)g,
                                   (__attribute__((address_space(3))) unsigned int*)l, 16, 0, 0);
}

#define NPAD   16640      // 65*256 padded proj width (16448 real)
#define DI     4096
#define SCALEF 0.125f     // D_STATE^-0.5

// ---------------------------------------------------------------- cast f32->bf16
__global__ __launch_bounds__(256) void cast_f32_to_bf16(
    const float* __restrict__ src, uint16_t* __restrict__ dst, int n4)
{
  int i = blockIdx.x * 256 + threadIdx.x;
  if (i >= n4) return;
  const float4 v = ((const float4*)src)[i];
  uint64_t q = (uint64_t)f2b(v.x) | ((uint64_t)f2b(v.y) << 16)
             | ((uint64_t)f2b(v.z) << 32) | ((uint64_t)f2b(v.w) << 48);
  ((uint64_t*)dst)[i] = q;
}

// ---------------------------------------------------------------- GEMM1: proj = x @ W^T
// BM=BN=256, BK=64, 8 waves (2M x 4N), per-wave 128x64 C. Panel-chunked map (R8-proven).
// NEW (R9): B operand global->register direct (panel is L2/L3-resident), prefetched 1 tile
// ahead. LDS holds ONLY A (2 x 32KB dbuf) -> per-CU LDS traffic/K-tile 256KB -> 160KB.
// A-staging via gload_lds; boundary vmcnt(4) leaves newest B-prefetch in flight.
__global__ __launch_bounds__(512, 2) void gemm_bt6(
    const uint16_t* __restrict__ A, const uint16_t* __restrict__ Bw,
    uint16_t* __restrict__ Cout, float* __restrict__ dtraw)
{
  __shared__ __align__(16) uint16_t sA[2][256*64];   // 64 KB total
  const int tid = threadIdx.x, lane = tid & 63, wave = tid >> 6;
  // panel map: 13 panels x (16 mt x 5 nt), XCD-swizzle within panel (80 % 8 == 0)
  const int bid = blockIdx.x;
  const int pid = bid / 80;
  const int rr = bid - pid * 80;
  const int rs = (rr & 7) * 10 + (rr >> 3);
  const int mt = rs / 5;
  const int nt = pid * 5 + (rs - mt * 5);
  const int m0 = mt << 8, n0 = nt << 8;
  const int Krow = 2048, NT = 32;
  const int wm = wave >> 2, wn = wave & 3;

  // A staging: per call, 8 waves fill 64 rows; source unit pre-swizzled (lane&7)^(lane>>3)
  const int sr = lane >> 3;
  const int slu = ((lane & 7) ^ sr) << 3;
  const uint16_t* aS = A + (size_t)(m0 + wave*8 + sr) * Krow + slu;

  // A frag reads: logical unit u at phys u^(row&7)
  const int l15 = lane & 15;
  const int q = lane >> 4;
  const int u0 = ((q)     ^ (l15 & 7)) << 3;
  const int u1 = ((q + 4) ^ (l15 & 7)) << 3;
  const int abase = (wm*128 + l15) << 6;       // + mi*1024 (mi 0..7)

  // B direct: lane reads 16B at row n0+wn*64+ni*16+l15, k = t*64 + kh*32 + q*8
  const uint16_t* bRow0 = Bw + (size_t)(n0 + wn*64 +  0 + l15) * Krow + q*8;
  const uint16_t* bRow1 = Bw + (size_t)(n0 + wn*64 + 16 + l15) * Krow + q*8;
  const uint16_t* bRow2 = Bw + (size_t)(n0 + wn*64 + 32 + l15) * Krow + q*8;
  const uint16_t* bRow3 = Bw + (size_t)(n0 + wn*64 + 48 + l15) * Krow + q*8;

  facc4 acc[8][4] = {};
  bfrag8 a0[8], a1[8], bk0[4], bk1[4], bk0n[4], bk1n[4];

#define STA(bs, tt, c) gload_lds16(aS + (size_t)((c)*64)*Krow + (tt)*64, &sA[bs][((c)*64 + wave*8) << 6])
#define STAGE_A(bs, tt) do{ STA(bs,tt,0);STA(bs,tt,1);STA(bs,tt,2);STA(bs,tt,3); }while(0)
#define LDB(dst, tt, kh) do{ \
    dst[0] = *(const bfrag8*)(bRow0 + (tt)*64 + (kh)*32); \
    dst[1] = *(const bfrag8*)(bRow1 + (tt)*64 + (kh)*32); \
    dst[2] = *(const bfrag8*)(bRow2 + (tt)*64 + (kh)*32); \
    dst[3] = *(const bfrag8*)(bRow3 + (tt)*64 + (kh)*32); }while(0)

  // prologue: stage A(0), load B(0,k0); wait A landed (B may be in flight)
  STAGE_A(0, 0);
  LDB(bk0, 0, 0);
  asm volatile("s_waitcnt vmcnt(4)" ::: "memory");
  asm volatile("s_barrier" ::: "memory");
  __builtin_amdgcn_sched_barrier(0);
  #pragma unroll
  for (int i = 0; i < 8; i++) a0[i] = *(const bfrag8*)&sA[0][abase + i*1024 + u0];
  STAGE_A(1, 1);
  LDB(bk1, 0, 1);

  #pragma unroll 1
  for (int t = 0; t < NT; ++t){
    const int c = t & 1;
    const bool st  = (t + 1 < NT);
    const bool st2 = (t + 2 < NT);
    // reads for cluster 1 + B(k0) prefetch for t+1 (retire under cluster-0 MFMAs)
    #pragma unroll
    for (int i = 0; i < 8; i++) a1[i] = *(const bfrag8*)&sA[c][abase + i*1024 + u1];
    if (st){ LDB(bk0n, t+1, 0); }
    __builtin_amdgcn_sched_barrier(0);
    // cluster 0: a0 x B(k0)
    __builtin_amdgcn_s_setprio(1);
    #pragma unroll
    for (int mi = 0; mi < 8; mi++)
      #pragma unroll
      for (int ni = 0; ni < 4; ni++)
        acc[mi][ni] = __builtin_amdgcn_mfma_f32_16x16x32_bf16(a0[mi], bk0[ni], acc[mi][ni], 0, 0, 0);
    __builtin_amdgcn_s_setprio(0);
    __builtin_amdgcn_sched_barrier(0);
    asm volatile("s_waitcnt lgkmcnt(0)" ::: "memory");   // my a1 reads retired
    if (st){
      // A-stage(t+1) landed; newest 4 (bk0n) may stay in flight
      asm volatile("s_waitcnt vmcnt(4)" ::: "memory");
      asm volatile("s_barrier" ::: "memory");
    }
    __builtin_amdgcn_sched_barrier(0);
    if (st){
      // prefetch next tile's S0 frags from freshly staged buffer; stage t+2 into freed buf c
      #pragma unroll
      for (int i = 0; i < 8; i++) a0[i] = *(const bfrag8*)&sA[c ^ 1][abase + i*1024 + u0];
      if (st2){ STAGE_A(c, t + 2); }
      LDB(bk1n, t+1, 1);
    }
    __builtin_amdgcn_sched_barrier(0);
    // cluster 1: a1 x B(k1)
    __builtin_amdgcn_s_setprio(1);
    #pragma unroll
    for (int mi = 0; mi < 8; mi++)
      #pragma unroll
      for (int ni = 0; ni < 4; ni++)
        acc[mi][ni] = __builtin_amdgcn_mfma_f32_16x16x32_bf16(a1[mi], bk1[ni], acc[mi][ni], 0, 0, 0);
    __builtin_amdgcn_s_setprio(0);
    __builtin_amdgcn_sched_barrier(0);
    if (st){
      #pragma unroll
      for (int i = 0; i < 4; i++){ bk0[i] = bk0n[i]; bk1[i] = bk1n[i]; }
    }
  }
#undef STA
#undef STAGE_A
#undef LDB

  #pragma unroll
  for (int mi = 0; mi < 8; mi++)
    #pragma unroll
    for (int ni = 0; ni < 4; ni++)
      #pragma unroll
      for (int r2 = 0; r2 < 4; r2++){
        const int gm = m0 + wm*128 + mi*16 + (lane >> 4)*4 + r2;
        const int gn = n0 + wn*64 + ni*16 + l15;
        const float v = acc[mi][ni][r2];
        Cout[(size_t)gm * NPAD + gn] = f2b(v);
        if (gn >= 16384 && gn < 16448) dtraw[gm*64 + (gn - 16384)] = v;
      }
}

// ---------------------------------------------------------------- GEMM2: m97-class 128x128, 2 blocks/CU (f32 out)
__global__ __launch_bounds__(256, 2) void gemm97(
    const uint16_t* __restrict__ A, const uint16_t* __restrict__ Bw,
    float* __restrict__ Cout, int Ndim, int Krow, int ntiles)
{
  __shared__ __align__(16) uint16_t sA[2][128*64];
  __shared__ __align__(16) uint16_t sB[2][128*64];
  const int tid = threadIdx.x, lane = tid & 63, wave = tid >> 6;
  const int nwg = gridDim.x, bid = blockIdx.x;
  const int swzb = (bid & 7) * (nwg >> 3) + (bid >> 3);   // XCD swizzle, grid % 8 == 0
  const int mt = swzb / ntiles, nt = swzb - mt * ntiles;
  const int m0 = mt << 7, n0 = nt << 7;
  const int wm = wave >> 1, wn = wave & 1;
  const int NT = Krow >> 6;

  const int sr = lane >> 3;
  const int slu = ((lane & 7) ^ sr) << 3;
  const uint16_t* aS = A  + (size_t)(m0 + wave*8 + sr) * Krow + slu;
  const uint16_t* bS = Bw + (size_t)(n0 + wave*8 + sr) * Krow + slu;

  const int l15 = lane & 15;
  const int q = lane >> 4;
  const int u0 = ((q)     ^ (l15 & 7)) << 3;
  const int u1 = ((q + 4) ^ (l15 & 7)) << 3;
  const int abase = (wm*64 + l15) << 6;     // + mi*1024
  const int bbase = (wn*64 + l15) << 6;     // + ni*1024

  facc4 acc[4][4] = {};

#define GA(bs, tt, c) gload_lds16(aS + (size_t)((c)*32)*Krow + (tt)*64, &sA[bs][((c)*32 + wave*8) << 6])
#define GB(bs, tt, c) gload_lds16(bS + (size_t)((c)*32)*Krow + (tt)*64, &sB[bs][((c)*32 + wave*8) << 6])
#define STAGE(bs, tt) do{ GA(bs,tt,0);GA(bs,tt,1);GA(bs,tt,2);GA(bs,tt,3); \
                          GB(bs,tt,0);GB(bs,tt,1);GB(bs,tt,2);GB(bs,tt,3); }while(0)

  STAGE(0, 0);
  asm volatile("s_waitcnt vmcnt(0)" ::: "memory");
  asm volatile("s_barrier" ::: "memory");
  __builtin_amdgcn_sched_barrier(0);

  #pragma unroll 1
  for (int t = 0; t < NT; ++t){
    const int c = t & 1;
    const bool st = (t + 1 < NT);
    const uint16_t* sa = sA[c];
    const uint16_t* sb = sB[c];
    if (st){ STAGE(c ^ 1, t + 1); }
    bfrag8 af[2][4], bf[2][4];
    #pragma unroll
    for (int mi = 0; mi < 4; mi++){
      af[0][mi] = *(const bfrag8*)&sa[abase + mi*1024 + u0];
      af[1][mi] = *(const bfrag8*)&sa[abase + mi*1024 + u1];
    }
    #pragma unroll
    for (int ni = 0; ni < 4; ni++){
      bf[0][ni] = *(const bfrag8*)&sb[bbase + ni*1024 + u0];
      bf[1][ni] = *(const bfrag8*)&sb[bbase + ni*1024 + u1];
    }
    __builtin_amdgcn_sched_barrier(0);
    __builtin_amdgcn_s_setprio(1);
    #pragma unroll
    for (int ks = 0; ks < 2; ks++)
      #pragma unroll
      for (int mi = 0; mi < 4; mi++)
        #pragma unroll
        for (int ni = 0; ni < 4; ni++)
          acc[mi][ni] = __builtin_amdgcn_mfma_f32_16x16x32_bf16(af[ks][mi], bf[ks][ni], acc[mi][ni], 0, 0, 0);
    __builtin_amdgcn_s_setprio(0);
    __builtin_amdgcn_sched_barrier(0);
    if (st){
      asm volatile("s_waitcnt vmcnt(0)" ::: "memory");
      asm volatile("s_barrier" ::: "memory");
      __builtin_amdgcn_sched_barrier(0);
    }
  }
#undef GA
#undef GB
#undef STAGE

  #pragma unroll
  for (int mi = 0; mi < 4; mi++)
    #pragma unroll
    for (int ni = 0; ni < 4; ni++)
      #pragma unroll
      for (int r = 0; r < 4; r++){
        const int gm = m0 + wm*64 + mi*16 + (lane >> 4)*4 + r;
        const int gn = n0 + wn*64 + ni*16 + l15;
        Cout[(size_t)gm * Ndim + gn] = acc[mi][ni][r];
      }
}

// ---------------------------------------------------------------- dt = clip(softplus(dtraw+bias)), cumsum(A*dt)
__global__ __launch_bounds__(256) void dt_cum(
    const float* __restrict__ dtraw, const float* __restrict__ A_log, const float* __restrict__ dt_bias,
    float* __restrict__ dtb, float* __restrict__ cumb, float* __restrict__ ctotb)
{
  const int g = blockIdx.x*4 + (threadIdx.x >> 6);   // (b*8+c)*64+h
  const int lane = threadIdx.x & 63;
  const int h = g & 63;
  const int r0 = (g >> 6) << 8;
  const float A = -__expf(A_log[h]);
  const float bias = dt_bias[h];
  float loc[4], s = 0.f;
  #pragma unroll
  for (int k = 0; k < 4; k++){
    const int l = lane*4 + k;
    const float xr = dtraw[(size_t)(r0 + l)*64 + h] + bias;
    const float sp = (xr > 20.f) ? xr : log1pf(__expf(xr));
    const float dt = fminf(fmaxf(sp, 1e-4f), 0.5f);
    dtb[g*256 + l] = dt;
    s += A * dt;
    loc[k] = s;
  }
  float run = s;
  #pragma unroll
  for (int off = 1; off < 64; off <<= 1){
    const float tmp = __shfl_up(run, off);
    if (lane >= off) run += tmp;
  }
  const float excl = run - s;
  #pragma unroll
  for (int k = 0; k < 4; k++) cumb[g*256 + lane*4 + k] = excl + loc[k];
  if (lane == 63) ctotb[g] = run;
}

// ---------------------------------------------------------------- pass1: per (b,c,h) conv+SiLU fused, y_intra + delta_h
__global__ __launch_bounds__(256) void chunk_pass1(
    const uint16_t* __restrict__ projb, const float* __restrict__ conv_w,
    const float* __restrict__ dtb, const float* __restrict__ cumb,
    const float* __restrict__ ctotb, uint16_t* __restrict__ yvb, float* __restrict__ dh)
{
  __shared__ __align__(16) uint16_t sCc[256*64];   // C tile, [l][n] XOR-swz
  __shared__ __align__(16) uint16_t sBc[256*64];   // B tile, [l][n] XOR-swz
  __shared__ __align__(16) uint16_t sXT[64*256];   // (xconv*dt)^T  [p][l] swz u^(p&7)^(p>>3)
  __shared__ __align__(16) uint16_t sBT[64*256];   // (B*dte)^T  [n][l] same swz
  __shared__ __align__(16) uint16_t sS[4][64*32];  // per-wave S strip [i][j] swz
  __shared__ float sCum[256];
  __shared__ float sDt[256];
  __shared__ float sDte[256];

  const int tid = threadIdx.x, lane = tid & 63, wave = tid >> 6;
  const int bx = blockIdx.x;                // ((b*8+c)*64 + h)
  const int h = bx & 63;
  const int r0 = (bx >> 6) << 8;            // global row base b*2048 + c*256

  // stage Cc/Bc via global_load_lds, source-swizzled
  {
    const int Ccol = 12288 + h*64;
    const int Bcol = 8192 + h*64;
    const int sr = lane >> 3;
    const int lu = (lane & 7) ^ (sr & 7);
    const uint16_t* cS = projb + (size_t)(r0 + wave*64 + sr)*NPAD + Ccol + lu*8;
    const uint16_t* bS = projb + (size_t)(r0 + wave*64 + sr)*NPAD + Bcol + lu*8;
    uint16_t* cD = sCc + wave*4096;
    uint16_t* bD = sBc + wave*4096;
    #pragma unroll
    for (int i = 0; i < 8; i++){
      gload_lds16(cS + (size_t)(i*8)*NPAD, cD + i*512);
      gload_lds16(bS + (size_t)(i*8)*NPAD, bD + i*512);
    }
  }
  const float ctot = ctotb[bx];
  {
    const float cv = cumb[bx*256 + tid];
    sCum[tid] = cv;
    sDt[tid]  = dtb[bx*256 + tid];
    sDte[tid] = __expf(ctot - cv);          // decay_to_end
  }
  __syncthreads();

  // reg-scatter transposed tiles; x comes from fused depthwise conv(4)+SiLU
  {
    const int lsub = tid >> 3;              // 0..31
    const int p0 = (tid & 7) * 8;
    float wc[8][4];
    #pragma unroll
    for (int k = 0; k < 8; k++){
      const float4 ww = *(const float4*)(conv_w + (size_t)(h*64 + p0 + k)*4);
      wc[k][0]=ww.x; wc[k][1]=ww.y; wc[k][2]=ww.z; wc[k][3]=ww.w;
    }
    #pragma unroll
    for (int rep = 0; rep < 8; rep++){
      const int l = rep*32 + lsub;
      const float dtl = sDt[l];
      const float dte = sDte[l];
      // depthwise conv over global-time within batch
      float ca[8] = {0,0,0,0,0,0,0,0};
      const int tb = (r0 & 2047) + l;       // t within batch
      #pragma unroll
      for (int j = 0; j < 4; j++){
        if (tb - 3 + j >= 0){
          const bfrag8 px = *(const bfrag8*)(projb + (size_t)(r0 + l - 3 + j)*NPAD + DI + h*64 + p0);
          #pragma unroll
          for (int k = 0; k < 8; k++) ca[k] += b2f((uint16_t)px[k]) * wc[k][j];
        }
      }
      const bfrag8 vb = *(const bfrag8*)(projb + (size_t)(r0 + l)*NPAD + 8192 + h*64 + p0);
      const int usrc = l >> 3;
      const int lrem = l & 7;
      #pragma unroll
      for (int k = 0; k < 8; k++){
        const int p = p0 + k;
        const int phys = usrc ^ (p & 7) ^ (p >> 3);
        const float xv = ca[k] / (1.f + __expf(-ca[k]));   // SiLU
        sXT[p*256 + phys*8 + lrem] = f2b(xv * dtl);
        sBT[p*256 + phys*8 + lrem] = f2b(b2f((uint16_t)vb[k]) * dte);
      }
    }
  }
  __syncthreads();

  const int i0 = wave * 64;                 // this wave's i-strip
  facc4 yacc[4][4] = {};

  #pragma unroll 1
  for (int jt = 0; jt < 8; jt++){
    // S'[j,i] = B @ C^T  (swapped so repack is contiguous b64 writes)
    facc4 sacc[2][4] = {};
    #pragma unroll
    for (int ks = 0; ks < 2; ks++){
      bfrag8 aB[2], bC[4];
      #pragma unroll
      for (int jf = 0; jf < 2; jf++){
        const int j = jt*32 + jf*16 + (lane & 15);
        const int u = ks*4 + (lane >> 4);
        aB[jf] = *(const bfrag8*)(sBc + j*64 + ((u ^ (j & 7)) << 3));
      }
      #pragma unroll
      for (int f = 0; f < 4; f++){
        const int i = i0 + f*16 + (lane & 15);
        const int u = ks*4 + (lane >> 4);
        bC[f] = *(const bfrag8*)(sCc + i*64 + ((u ^ (i & 7)) << 3));
      }
      #pragma unroll
      for (int jf = 0; jf < 2; jf++)
        #pragma unroll
        for (int f = 0; f < 4; f++)
          sacc[jf][f] = __builtin_amdgcn_mfma_f32_16x16x32_bf16(aB[jf], bC[f], sacc[jf][f], 0, 0, 0);
    }
    // decay*SCALE, causal mask, pack bf16 -> per-wave S strip [i][j]
    #pragma unroll
    for (int jf = 0; jf < 2; jf++)
      #pragma unroll
      for (int f = 0; f < 4; f++){
        const int iloc = f*16 + (lane & 15);
        const float cumi = sCum[i0 + iloc];
        uint64_t pk = 0;
        #pragma unroll
        for (int r = 0; r < 4; r++){
          const int j = jt*32 + jf*16 + (lane >> 4)*4 + r;
          float v = 0.f;
          if (j <= i0 + iloc)
            v = sacc[jf][f][r] * SCALEF * __expf(cumi - sCum[j]);
          pk |= ((uint64_t)f2b(v)) << (16*r);
        }
        const int jl = jf*16 + (lane >> 4)*4;
        const int phys2 = (jl >> 3) ^ (iloc & 3);
        *(uint64_t*)(&sS[wave][iloc*32 + phys2*8 + (jl & 7)]) = pk;
      }
    // y_intra += S_strip @ xdt   (A from strip, B from sXT)
    bfrag8 bX[4];
    #pragma unroll
    for (int pf = 0; pf < 4; pf++){
      const int p = pf*16 + (lane & 15);
      const int u = jt*4 + (lane >> 4);
      bX[pf] = *(const bfrag8*)(sXT + p*256 + ((u ^ (p & 7) ^ (p >> 3)) << 3));
    }
    #pragma unroll
    for (int f = 0; f < 4; f++){
      const int iloc = f*16 + (lane & 15);
      const int phys2 = (lane >> 4) ^ (iloc & 3);
      const bfrag8 aS = *(const bfrag8*)(&sS[wave][iloc*32 + phys2*8]);
      #pragma unroll
      for (int pf = 0; pf < 4; pf++)
        yacc[f][pf] = __builtin_amdgcn_mfma_f32_16x16x32_bf16(aS, bX[pf], yacc[f][pf], 0, 0, 0);
    }
  }

  // delta_h[p,n] = sum_l (xconv*dt)[l,p] * (B*dte)[l,n]; wave owns p-strip wave*16
  facc4 dacc[4] = {};
  #pragma unroll
  for (int ks = 0; ks < 8; ks++){
    const int p = wave*16 + (lane & 15);
    const int u = ks*4 + (lane >> 4);
    const bfrag8 aX = *(const bfrag8*)(sXT + p*256 + ((u ^ (p & 7) ^ (p >> 3)) << 3));
    #pragma unroll
    for (int nf = 0; nf < 4; nf++){
      const int n = nf*16 + (lane & 15);
      const bfrag8 bB = *(const bfrag8*)(sBT + n*256 + ((u ^ (n & 7) ^ (n >> 3)) << 3));
      dacc[nf] = __builtin_amdgcn_mfma_f32_16x16x32_bf16(aX, bB, dacc[nf], 0, 0, 0);
    }
  }

  #pragma unroll
  for (int f = 0; f < 4; f++)
    #pragma unroll
    for (int pf = 0; pf < 4; pf++)
      #pragma unroll
      for (int r = 0; r < 4; r++){
        const int i = i0 + f*16 + (lane >> 4)*4 + r;
        const int p = pf*16 + (lane & 15);
        yvb[(size_t)(r0 + i)*DI + h*64 + p] = f2b(yacc[f][pf][r]);
      }
  #pragma unroll
  for (int nf = 0; nf < 4; nf++)
    #pragma unroll
    for (int r = 0; r < 4; r++){
      const int p = wave*16 + (lane >> 4)*4 + r;
      const int n = nf*16 + (lane & 15);
      dh[(size_t)bx*4096 + p*64 + n] = dacc[nf][r];
    }
}

// ---------------------------------------------------------------- cross-chunk state scan (8 steps)
__global__ __launch_bounds__(256) void scan_states(
    const float* __restrict__ dh, const float* __restrict__ ctotb, float* __restrict__ states)
{
  const int bh = blockIdx.x;                // b*64 + h
  const int b = bh >> 6, h = bh & 63;
  const int tid = threadIdx.x;
  float st[16];
  #pragma unroll
  for (int k = 0; k < 16; k++) st[k] = 0.f;
  for (int c = 0; c < 8; c++){
    const int g = (b*8 + c)*64 + h;
    const size_t base = (size_t)g * 4096;
    const float cd = __expf(ctotb[g]);
    #pragma unroll
    for (int k = 0; k < 4; k++){
      const int e = tid*4 + k*1024;
      float4 o; o.x = st[k*4]; o.y = st[k*4+1]; o.z = st[k*4+2]; o.w = st[k*4+3];
      *(float4*)(states + base + e) = o;    // state BEFORE chunk c
      const float4 d = *(const float4*)(dh + base + e);
      st[k*4]   = cd*st[k*4]   + d.x;
      st[k*4+1] = cd*st[k*4+1] + d.y;
      st[k*4+2] = cd*st[k*4+2] + d.z;
      st[k*4+3] = cd*st[k*4+3] + d.w;
    }
  }
}

// ---------------------------------------------------------------- pass2: y += exp(cum)*SCALE * C @ h^T  (bf16 RMW)
__global__ __launch_bounds__(256) void chunk_pass2(
    const uint16_t* __restrict__ projb, const float* __restrict__ states,
    const float* __restrict__ cumb, uint16_t* __restrict__ yvb)
{
  __shared__ __align__(16) uint16_t sCc[256*64];
  __shared__ __align__(16) uint16_t sH[64*64];    // [p][n] swz
  __shared__ float sCum[256];
  const int tid = threadIdx.x, lane = tid & 63, wave = tid >> 6;
  const int bx = blockIdx.x, h = bx & 63, r0 = (bx >> 6) << 8;
  {
    const int Ccol = 12288 + h*64;
    const int sr = lane >> 3;
    const int lu = (lane & 7) ^ (sr & 7);
    const uint16_t* cS = projb + (size_t)(r0 + wave*64 + sr)*NPAD + Ccol + lu*8;
    uint16_t* cD = sCc + wave*4096;
    #pragma unroll
    for (int i = 0; i < 8; i++) gload_lds16(cS + (size_t)(i*8)*NPAD, cD + i*512);
  }
  #pragma unroll
  for (int k = 0; k < 4; k++){
    const int e = tid*4 + k*1024;
    const float4 v = *(const float4*)(states + (size_t)bx*4096 + e);
    const int p = e >> 6, n0 = e & 63;
    const int phys = (n0 >> 3) ^ (p & 7);
    uint64_t pk = (uint64_t)f2b(v.x) | ((uint64_t)f2b(v.y) << 16)
                | ((uint64_t)f2b(v.z) << 32) | ((uint64_t)f2b(v.w) << 48);
    *(uint64_t*)(&sH[p*64 + phys*8 + (n0 & 7)]) = pk;
  }
  sCum[tid] = cumb[bx*256 + tid];
  __syncthreads();

  const int i0 = wave*64;
  facc4 acc[4][4] = {};
  #pragma unroll
  for (int ks = 0; ks < 2; ks++){
    bfrag8 aC[4], bH[4];
    #pragma unroll
    for (int f = 0; f < 4; f++){
      const int i = i0 + f*16 + (lane & 15);
      const int u = ks*4 + (lane >> 4);
      aC[f] = *(const bfrag8*)(sCc + i*64 + ((u ^ (i & 7)) << 3));
    }
    #pragma unroll
    for (int pf = 0; pf < 4; pf++){
      const int p = pf*16 + (lane & 15);
      const int u = ks*4 + (lane >> 4);
      bH[pf] = *(const bfrag8*)(sH + p*64 + ((u ^ (p & 7)) << 3));
    }
    #pragma unroll
    for (int f = 0; f < 4; f++)
      #pragma unroll
      for (int pf = 0; pf < 4; pf++)
        acc[f][pf] = __builtin_amdgcn_mfma_f32_16x16x32_bf16(aC[f], bH[pf], acc[f][pf], 0, 0, 0);
  }
  #pragma unroll
  for (int f = 0; f < 4; f++)
    #pragma unroll
    for (int r = 0; r < 4; r++){
      const int i = i0 + f*16 + (lane >> 4)*4 + r;
      const float sc = SCALEF * __expf(sCum[i]);
      #pragma unroll
      for (int pf = 0; pf < 4; pf++){
        const int p = pf*16 + (lane & 15);
        uint16_t* yp = yvb + (size_t)(r0 + i)*DI + h*64 + p;
        *yp = f2b(b2f(*yp) + acc[f][pf][r] * sc);
      }
    }
}

// ---------------------------------------------------------------- RMSNorm + SiLU(z) gate -> bf16
__global__ __launch_bounds__(256) void norm_gate(
    const uint16_t* __restrict__ yvb, const uint16_t* __restrict__ projb, uint16_t* __restrict__ yb)
{
  const int row = blockIdx.x, tid = threadIdx.x;
  float v[16];
  float ss = 0.f;
  #pragma unroll
  for (int k = 0; k < 2; k++){
    const bfrag8 y8 = *(const bfrag8*)(yvb + (size_t)row*DI + tid*8 + k*2048);
    #pragma unroll
    for (int j = 0; j < 8; j++){
      const float f = b2f((uint16_t)y8[j]);
      v[k*8+j] = f;
      ss += f*f;
    }
  }
  #pragma unroll
  for (int off = 32; off > 0; off >>= 1) ss += __shfl_down(ss, off);
  __shared__ float red[4];
  if ((tid & 63) == 0) red[tid >> 6] = ss;
  __syncthreads();
  const float inv = rsqrtf((red[0]+red[1]+red[2]+red[3]) * (1.f/4096.f) + 1.1920929e-07f);
  #pragma unroll
  for (int k = 0; k < 2; k++){
    const int e = tid*8 + k*2048;
    const bfrag8 z8 = *(const bfrag8*)(projb + (size_t)row*NPAD + e);
    uint16_t o[8];
    #pragma unroll
    for (int j = 0; j < 8; j++){
      const float z = b2f((uint16_t)z8[j]);
      const float g = z / (1.f + __expf(-z));
      o[j] = f2b(v[k*8+j] * inv * g);
    }
    uint4 pk;
    pk.x = (uint32_t)o[0] | ((uint32_t)o[1] << 16);
    pk.y = (uint32_t)o[2] | ((uint32_t)o[3] << 16);
    pk.z = (uint32_t)o[4] | ((uint32_t)o[5] << 16);
    pk.w = (uint32_t)o[6] | ((uint32_t)o[7] << 16);
    *(uint4*)(yb + (size_t)row*DI + e) = pk;
  }
}

// ---------------------------------------------------------------- launcher
extern "C" void kernel_launch(void* const* d_in, const int* in_sizes, int n_in,
                              void* d_out, int out_size, void* d_ws, size_t ws_size,
                              hipStream_t stream)
{
  (void)in_sizes; (void)n_in; (void)out_size; (void)ws_size;
  const float* x         = (const float*)d_in[0];
  const float* in_proj_w = (const float*)d_in[1];
  const float* conv_w    = (const float*)d_in[2];
  const float* A_log     = (const float*)d_in[3];
  const float* dt_bias   = (const float*)d_in[4];
  const float* out_proj_w= (const float*)d_in[5];
  float* out = (float*)d_out;

  char* ws = (char*)d_ws;
  uint16_t* xb    = (uint16_t*)(ws + 0);               // 4096x2048 bf16 = 16.8MB (dead after gemm1)
  uint16_t* yvb   = (uint16_t*)(ws + 0);               // 4096x4096 bf16 = 33.5MB (overlaps xb + wb head)
  uint16_t* wb    = (uint16_t*)(ws + 16777216);        // 16640x2048 bf16 -> end 84,934,656 (dead after gemm1)
  uint16_t* projb = (uint16_t*)(ws + 84934656);        // 4096x16640 bf16 -> end 221,249,536
  float* dtraw    = (float*)(ws + 221249536);          // 4096x64 f32
  float* dtb      = (float*)(ws + 222298112);          // 1024x256 f32
  float* cumb     = (float*)(ws + 223346688);          // 1024x256 f32
  float* ctotb    = (float*)(ws + 224395264);          // 1024 f32
  uint16_t* yb    = (uint16_t*)(ws + 224399360);       // 4096x4096 bf16 -> 257,953,792
  float* dh       = (float*)(ws + 257953792);          // 1024x64x64 f32 -> 274,731,008
  float* states   = (float*)(ws + 274731008);          // 1024x64x64 f32 -> 291,508,224
  uint16_t* opb   = (uint16_t*)(ws + 291508224);       // 2048x4096 bf16 -> 308,285,440

  // casts
  cast_f32_to_bf16<<<8192, 256, 0, stream>>>(x, xb, 2097152);
  cast_f32_to_bf16<<<32896, 256, 0, stream>>>(in_proj_w, wb, 8421376);
  hipMemsetAsync(wb + (size_t)16448*2048, 0, (size_t)192*2048*2, stream);   // zero pad rows of W
  cast_f32_to_bf16<<<8192, 256, 0, stream>>>(out_proj_w, opb, 2097152);

  // in_proj GEMM (bf16 out + f32 dtraw side-channel): panel-chunked 13 x (16mt x 5nt)
  gemm_bt6<<<1040, 512, 0, stream>>>(xb, wb, projb, dtraw);

  dt_cum<<<256, 256, 0, stream>>>(dtraw, A_log, dt_bias, dtb, cumb, ctotb);
  chunk_pass1<<<1024, 256, 0, stream>>>(projb, conv_w, dtb, cumb, ctotb, yvb, dh);
  scan_states<<<128, 256, 0, stream>>>(dh, ctotb, states);
  chunk_pass2<<<1024, 256, 0, stream>>>(projb, states, cumb, yvb);
  norm_gate<<<4096, 256, 0, stream>>>(yvb, projb, yb);

  // out_proj GEMM: 128x128 tiles, 32 mt x 16 nt = 512 blocks, 2 blocks/CU, direct f32 out
  gemm97<<<512, 256, 0, stream>>>(yb, opb, out, 2048, 4096, 16);
}

// Round 10
// 608.677 us; speedup vs baseline: 2.0027x; 2.0027x over previous
//
#include <hip/hip_runtime.h>
#include <cstdint>
#include <cstddef>

// ---------------------------------------------------------------- types/helpers
typedef __attribute__((ext_vector_type(8))) short bfrag8;   // 8 bf16 = 4 VGPR (MFMA A/B frag)
typedef __attribute__((ext_vector_type(4))) float facc4;    // MFMA C/D frag

#define DEV static __device__ __forceinline__

DEV uint16_t f2b(float f){                       // f32 -> bf16, RNE
  uint32_t b = __builtin_bit_cast(uint32_t, f);
  return (uint16_t)((b + 0x7FFFu + ((b >> 16) & 1u)) >> 16);
}
DEV float b2f(uint16_t h){
  uint32_t b = ((uint32_t)h) << 16;
  return __builtin_bit_cast(float, b);
}
DEV void gload_lds16(const void* g, void* l){    // async global->LDS, 16B/lane
  __builtin_amdgcn_global_load_lds((const __attribute__((address_space(1))) unsigned int*)g,
                                   (__attribute__((address_space(3))) unsigned int*)l, 16, 0, 0);
}

#define NPAD   16640      // 65*256 padded proj width (16448 real)
#define DI     4096
#define SCALEF 0.125f     // D_STATE^-0.5

// ---------------------------------------------------------------- cast f32->bf16
__global__ __launch_bounds__(256) void cast_f32_to_bf16(
    const float* __restrict__ src, uint16_t* __restrict__ dst, int n4)
{
  int i = blockIdx.x * 256 + threadIdx.x;
  if (i >= n4) return;
  const float4 v = ((const float4*)src)[i];
  uint64_t q = (uint64_t)f2b(v.x) | ((uint64_t)f2b(v.y) << 16)
             | ((uint64_t)f2b(v.z) << 32) | ((uint64_t)f2b(v.w) << 48);
  ((uint64_t*)dst)[i] = q;
}

// ---------------------------------------------------------------- GEMM1: proj = x @ W^T, 4-phase counted-vmcnt + panels
// BM=BN=256, BK=64, 8 waves (2M x 4N), per-wave 128x64 C (acc[8][4]). 2 LDS buffers (128KB).
// 4 phases/K-tile of 16 MFMA: {ks0,A-low},{ks0,A-high},{ks1,A-low},{ks1,A-high}.
// Staging of tile t+1 during t: ph1 B{0,1}, ph2 B{2,3}, ph3 A{0,2}, ph4 A{1,3}.
// Counted vmcnt(2) at ph1-end (releases t's A1,A3) and ph4-end (releases t+1's B0-3,A0,A2).
// Never drains to 0 mid-loop. Ring verified: outstanding counts {4,4,6,8} at the two waits.
// PANEL map (R8-proven, removes HBM co-limit): 13 panels x (16 mt x 5 nt), XCD-swizzled within panel.
// bf16 out (ld=NPAD) + f32 dtraw side-channel cols[16384,16448).
__global__ __launch_bounds__(512, 2) void gemm_bt7(
    const uint16_t* __restrict__ A, const uint16_t* __restrict__ Bw,
    uint16_t* __restrict__ Cout, float* __restrict__ dtraw)
{
  __shared__ __align__(16) uint16_t sA[2][256*64];
  __shared__ __align__(16) uint16_t sB[2][256*64];
  const int tid = threadIdx.x, lane = tid & 63, wave = tid >> 6;
  // panel map
  const int bid = blockIdx.x;
  const int pid = bid / 80;
  const int rr = bid - pid * 80;
  const int rs = (rr & 7) * 10 + (rr >> 3);
  const int mt = rs / 5;
  const int nt = pid * 5 + (rs - mt * 5);
  const int m0 = mt << 8, n0 = nt << 8;
  const int Krow = 2048, NT = 32;
  const int wm = wave >> 2, wn = wave & 3;

  // staging: per call, all 8 waves fill 64 rows (wave*8 + lane>>3); lane unit (lane&7),
  // source unit pre-swizzled (lane&7)^(lane>>3) so phys u holds logical u^(row&7).
  const int sr = lane >> 3;
  const int slu = ((lane & 7) ^ sr) << 3;
  const uint16_t* aS = A  + (size_t)(m0 + wave*8 + sr) * Krow + slu;
  const uint16_t* bS = Bw + (size_t)(n0 + wave*8 + sr) * Krow + slu;

  // frag-read constants: logical unit u at phys u^(row&7)
  const int l15 = lane & 15;
  const int q = lane >> 4;
  const int u0 = ((q)     ^ (l15 & 7)) << 3;
  const int u1 = ((q + 4) ^ (l15 & 7)) << 3;
  const int abase = (wm*128 + l15) << 6;       // + mi*1024 (mi 0..7)
  const int bbase = (wn*64  + l15) << 6;       // + ni*1024

  facc4 acc[8][4] = {};

#define STA(bs, tt, c) gload_lds16(aS + (size_t)((c)*64)*Krow + (tt)*64, &sA[bs][((c)*64 + wave*8) << 6])
#define STB(bs, tt, c) gload_lds16(bS + (size_t)((c)*64)*Krow + (tt)*64, &sB[bs][((c)*64 + wave*8) << 6])

  // prologue: stage tile 0 in consumption order; first-6 landed before entry
  STB(0,0,0); STB(0,0,1); STB(0,0,2); STB(0,0,3);
  STA(0,0,0); STA(0,0,2); STA(0,0,1); STA(0,0,3);
  asm volatile("s_waitcnt vmcnt(2)" ::: "memory");
  asm volatile("s_barrier" ::: "memory");
  __builtin_amdgcn_sched_barrier(0);

  #pragma unroll 1
  for (int t = 0; t < NT; ++t){
    const int cur = t & 1, stg = cur ^ 1;
    const bool st = (t + 1 < NT);
    const uint16_t* sa = sA[cur];
    const uint16_t* sb = sB[cur];
    bfrag8 bf[4], af[4];
    // ---------- phase 1: ks0 x A-low ----------
    #pragma unroll
    for (int ni = 0; ni < 4; ni++) bf[ni] = *(const bfrag8*)&sb[bbase + ni*1024 + u0];
    #pragma unroll
    for (int mi = 0; mi < 4; mi++) af[mi] = *(const bfrag8*)&sa[abase + mi*1024 + u0];
    if (st){ STB(stg, t+1, 0); STB(stg, t+1, 1); }
    asm volatile("s_barrier" ::: "memory");
    asm volatile("s_waitcnt lgkmcnt(0)" ::: "memory");
    __builtin_amdgcn_sched_barrier(0);
    __builtin_amdgcn_s_setprio(1);
    #pragma unroll
    for (int mi = 0; mi < 4; mi++)
      #pragma unroll
      for (int ni = 0; ni < 4; ni++)
        acc[mi][ni] = __builtin_amdgcn_mfma_f32_16x16x32_bf16(af[mi], bf[ni], acc[mi][ni], 0, 0, 0);
    __builtin_amdgcn_s_setprio(0);
    __builtin_amdgcn_sched_barrier(0);
    if (st) asm volatile("s_waitcnt vmcnt(2)" ::: "memory");   // t's A1,A3 landed
    else    asm volatile("s_waitcnt vmcnt(0)" ::: "memory");   // last tile drain
    asm volatile("s_barrier" ::: "memory");
    __builtin_amdgcn_sched_barrier(0);
    // ---------- phase 2: ks0 x A-high ----------
    #pragma unroll
    for (int mi = 0; mi < 4; mi++) af[mi] = *(const bfrag8*)&sa[abase + (4+mi)*1024 + u0];
    if (st){ STB(stg, t+1, 2); STB(stg, t+1, 3); }
    asm volatile("s_barrier" ::: "memory");
    asm volatile("s_waitcnt lgkmcnt(0)" ::: "memory");
    __builtin_amdgcn_sched_barrier(0);
    __builtin_amdgcn_s_setprio(1);
    #pragma unroll
    for (int mi = 0; mi < 4; mi++)
      #pragma unroll
      for (int ni = 0; ni < 4; ni++)
        acc[4+mi][ni] = __builtin_amdgcn_mfma_f32_16x16x32_bf16(af[mi], bf[ni], acc[4+mi][ni], 0, 0, 0);
    __builtin_amdgcn_s_setprio(0);
    __builtin_amdgcn_sched_barrier(0);
    asm volatile("s_barrier" ::: "memory");
    __builtin_amdgcn_sched_barrier(0);
    // ---------- phase 3: ks1 x A-low ----------
    #pragma unroll
    for (int ni = 0; ni < 4; ni++) bf[ni] = *(const bfrag8*)&sb[bbase + ni*1024 + u1];
    #pragma unroll
    for (int mi = 0; mi < 4; mi++) af[mi] = *(const bfrag8*)&sa[abase + mi*1024 + u1];
    if (st){ STA(stg, t+1, 0); STA(stg, t+1, 2); }
    asm volatile("s_barrier" ::: "memory");
    asm volatile("s_waitcnt lgkmcnt(0)" ::: "memory");
    __builtin_amdgcn_sched_barrier(0);
    __builtin_amdgcn_s_setprio(1);
    #pragma unroll
    for (int mi = 0; mi < 4; mi++)
      #pragma unroll
      for (int ni = 0; ni < 4; ni++)
        acc[mi][ni] = __builtin_amdgcn_mfma_f32_16x16x32_bf16(af[mi], bf[ni], acc[mi][ni], 0, 0, 0);
    __builtin_amdgcn_s_setprio(0);
    __builtin_amdgcn_sched_barrier(0);
    asm volatile("s_barrier" ::: "memory");
    __builtin_amdgcn_sched_barrier(0);
    // ---------- phase 4: ks1 x A-high ----------
    #pragma unroll
    for (int mi = 0; mi < 4; mi++) af[mi] = *(const bfrag8*)&sa[abase + (4+mi)*1024 + u1];
    if (st){ STA(stg, t+1, 1); STA(stg, t+1, 3); }
    asm volatile("s_barrier" ::: "memory");
    asm volatile("s_waitcnt lgkmcnt(0)" ::: "memory");
    __builtin_amdgcn_sched_barrier(0);
    __builtin_amdgcn_s_setprio(1);
    #pragma unroll
    for (int mi = 0; mi < 4; mi++)
      #pragma unroll
      for (int ni = 0; ni < 4; ni++)
        acc[4+mi][ni] = __builtin_amdgcn_mfma_f32_16x16x32_bf16(af[mi], bf[ni], acc[4+mi][ni], 0, 0, 0);
    __builtin_amdgcn_s_setprio(0);
    __builtin_amdgcn_sched_barrier(0);
    if (t < NT - 1){
      asm volatile("s_waitcnt vmcnt(2)" ::: "memory");  // t+1's B0-3,A0,A2 landed
      asm volatile("s_barrier" ::: "memory");
      __builtin_amdgcn_sched_barrier(0);
    }
  }
#undef STA
#undef STB

  #pragma unroll
  for (int mi = 0; mi < 8; mi++)
    #pragma unroll
    for (int ni = 0; ni < 4; ni++)
      #pragma unroll
      for (int r2 = 0; r2 < 4; r2++){
        const int gm = m0 + wm*128 + mi*16 + (lane >> 4)*4 + r2;
        const int gn = n0 + wn*64 + ni*16 + l15;
        const float v = acc[mi][ni][r2];
        Cout[(size_t)gm * NPAD + gn] = f2b(v);
        if (gn >= 16384 && gn < 16448) dtraw[gm*64 + (gn - 16384)] = v;
      }
}

// ---------------------------------------------------------------- GEMM2: m97-class 128x128, 2 blocks/CU (f32 out)
__global__ __launch_bounds__(256, 2) void gemm97(
    const uint16_t* __restrict__ A, const uint16_t* __restrict__ Bw,
    float* __restrict__ Cout, int Ndim, int Krow, int ntiles)
{
  __shared__ __align__(16) uint16_t sA[2][128*64];
  __shared__ __align__(16) uint16_t sB[2][128*64];
  const int tid = threadIdx.x, lane = tid & 63, wave = tid >> 6;
  const int nwg = gridDim.x, bid = blockIdx.x;
  const int swzb = (bid & 7) * (nwg >> 3) + (bid >> 3);   // XCD swizzle, grid % 8 == 0
  const int mt = swzb / ntiles, nt = swzb - mt * ntiles;
  const int m0 = mt << 7, n0 = nt << 7;
  const int wm = wave >> 1, wn = wave & 1;
  const int NT = Krow >> 6;

  const int sr = lane >> 3;
  const int slu = ((lane & 7) ^ sr) << 3;
  const uint16_t* aS = A  + (size_t)(m0 + wave*8 + sr) * Krow + slu;
  const uint16_t* bS = Bw + (size_t)(n0 + wave*8 + sr) * Krow + slu;

  const int l15 = lane & 15;
  const int q = lane >> 4;
  const int u0 = ((q)     ^ (l15 & 7)) << 3;
  const int u1 = ((q + 4) ^ (l15 & 7)) << 3;
  const int abase = (wm*64 + l15) << 6;     // + mi*1024
  const int bbase = (wn*64 + l15) << 6;     // + ni*1024

  facc4 acc[4][4] = {};

#define GA(bs, tt, c) gload_lds16(aS + (size_t)((c)*32)*Krow + (tt)*64, &sA[bs][((c)*32 + wave*8) << 6])
#define GB(bs, tt, c) gload_lds16(bS + (size_t)((c)*32)*Krow + (tt)*64, &sB[bs][((c)*32 + wave*8) << 6])
#define STAGE(bs, tt) do{ GA(bs,tt,0);GA(bs,tt,1);GA(bs,tt,2);GA(bs,tt,3); \
                          GB(bs,tt,0);GB(bs,tt,1);GB(bs,tt,2);GB(bs,tt,3); }while(0)

  STAGE(0, 0);
  asm volatile("s_waitcnt vmcnt(0)" ::: "memory");
  asm volatile("s_barrier" ::: "memory");
  __builtin_amdgcn_sched_barrier(0);

  #pragma unroll 1
  for (int t = 0; t < NT; ++t){
    const int c = t & 1;
    const bool st = (t + 1 < NT);
    const uint16_t* sa = sA[c];
    const uint16_t* sb = sB[c];
    if (st){ STAGE(c ^ 1, t + 1); }
    bfrag8 af[2][4], bf[2][4];
    #pragma unroll
    for (int mi = 0; mi < 4; mi++){
      af[0][mi] = *(const bfrag8*)&sa[abase + mi*1024 + u0];
      af[1][mi] = *(const bfrag8*)&sa[abase + mi*1024 + u1];
    }
    #pragma unroll
    for (int ni = 0; ni < 4; ni++){
      bf[0][ni] = *(const bfrag8*)&sb[bbase + ni*1024 + u0];
      bf[1][ni] = *(const bfrag8*)&sb[bbase + ni*1024 + u1];
    }
    __builtin_amdgcn_sched_barrier(0);
    __builtin_amdgcn_s_setprio(1);
    #pragma unroll
    for (int ks = 0; ks < 2; ks++)
      #pragma unroll
      for (int mi = 0; mi < 4; mi++)
        #pragma unroll
        for (int ni = 0; ni < 4; ni++)
          acc[mi][ni] = __builtin_amdgcn_mfma_f32_16x16x32_bf16(af[ks][mi], bf[ks][ni], acc[mi][ni], 0, 0, 0);
    __builtin_amdgcn_s_setprio(0);
    __builtin_amdgcn_sched_barrier(0);
    if (st){
      asm volatile("s_waitcnt vmcnt(0)" ::: "memory");
      asm volatile("s_barrier" ::: "memory");
      __builtin_amdgcn_sched_barrier(0);
    }
  }
#undef GA
#undef GB
#undef STAGE

  #pragma unroll
  for (int mi = 0; mi < 4; mi++)
    #pragma unroll
    for (int ni = 0; ni < 4; ni++)
      #pragma unroll
      for (int r = 0; r < 4; r++){
        const int gm = m0 + wm*64 + mi*16 + (lane >> 4)*4 + r;
        const int gn = n0 + wn*64 + ni*16 + l15;
        Cout[(size_t)gm * Ndim + gn] = acc[mi][ni][r];
      }
}

// ---------------------------------------------------------------- dt = clip(softplus(dtraw+bias)), cumsum(A*dt)
__global__ __launch_bounds__(256) void dt_cum(
    const float* __restrict__ dtraw, const float* __restrict__ A_log, const float* __restrict__ dt_bias,
    float* __restrict__ dtb, float* __restrict__ cumb, float* __restrict__ ctotb)
{
  const int g = blockIdx.x*4 + (threadIdx.x >> 6);   // (b*8+c)*64+h
  const int lane = threadIdx.x & 63;
  const int h = g & 63;
  const int r0 = (g >> 6) << 8;
  const float A = -__expf(A_log[h]);
  const float bias = dt_bias[h];
  float loc[4], s = 0.f;
  #pragma unroll
  for (int k = 0; k < 4; k++){
    const int l = lane*4 + k;
    const float xr = dtraw[(size_t)(r0 + l)*64 + h] + bias;
    const float sp = (xr > 20.f) ? xr : log1pf(__expf(xr));
    const float dt = fminf(fmaxf(sp, 1e-4f), 0.5f);
    dtb[g*256 + l] = dt;
    s += A * dt;
    loc[k] = s;
  }
  float run = s;
  #pragma unroll
  for (int off = 1; off < 64; off <<= 1){
    const float tmp = __shfl_up(run, off);
    if (lane >= off) run += tmp;
  }
  const float excl = run - s;
  #pragma unroll
  for (int k = 0; k < 4; k++) cumb[g*256 + lane*4 + k] = excl + loc[k];
  if (lane == 63) ctotb[g] = run;
}

// ---------------------------------------------------------------- pass1: per (b,c,h) conv+SiLU fused, y_intra + delta_h
__global__ __launch_bounds__(256) void chunk_pass1(
    const uint16_t* __restrict__ projb, const float* __restrict__ conv_w,
    const float* __restrict__ dtb, const float* __restrict__ cumb,
    const float* __restrict__ ctotb, uint16_t* __restrict__ yvb, float* __restrict__ dh)
{
  __shared__ __align__(16) uint16_t sCc[256*64];   // C tile, [l][n] XOR-swz
  __shared__ __align__(16) uint16_t sBc[256*64];   // B tile, [l][n] XOR-swz
  __shared__ __align__(16) uint16_t sXT[64*256];   // (xconv*dt)^T  [p][l] swz u^(p&7)^(p>>3)
  __shared__ __align__(16) uint16_t sBT[64*256];   // (B*dte)^T  [n][l] same swz
  __shared__ __align__(16) uint16_t sS[4][64*32];  // per-wave S strip [i][j] swz
  __shared__ float sCum[256];
  __shared__ float sDt[256];
  __shared__ float sDte[256];

  const int tid = threadIdx.x, lane = tid & 63, wave = tid >> 6;
  const int bx = blockIdx.x;                // ((b*8+c)*64 + h)
  const int h = bx & 63;
  const int r0 = (bx >> 6) << 8;            // global row base b*2048 + c*256

  // stage Cc/Bc via global_load_lds, source-swizzled
  {
    const int Ccol = 12288 + h*64;
    const int Bcol = 8192 + h*64;
    const int sr = lane >> 3;
    const int lu = (lane & 7) ^ (sr & 7);
    const uint16_t* cS = projb + (size_t)(r0 + wave*64 + sr)*NPAD + Ccol + lu*8;
    const uint16_t* bS = projb + (size_t)(r0 + wave*64 + sr)*NPAD + Bcol + lu*8;
    uint16_t* cD = sCc + wave*4096;
    uint16_t* bD = sBc + wave*4096;
    #pragma unroll
    for (int i = 0; i < 8; i++){
      gload_lds16(cS + (size_t)(i*8)*NPAD, cD + i*512);
      gload_lds16(bS + (size_t)(i*8)*NPAD, bD + i*512);
    }
  }
  const float ctot = ctotb[bx];
  {
    const float cv = cumb[bx*256 + tid];
    sCum[tid] = cv;
    sDt[tid]  = dtb[bx*256 + tid];
    sDte[tid] = __expf(ctot - cv);          // decay_to_end
  }
  __syncthreads();

  // reg-scatter transposed tiles; x comes from fused depthwise conv(4)+SiLU
  {
    const int lsub = tid >> 3;              // 0..31
    const int p0 = (tid & 7) * 8;
    float wc[8][4];
    #pragma unroll
    for (int k = 0; k < 8; k++){
      const float4 ww = *(const float4*)(conv_w + (size_t)(h*64 + p0 + k)*4);
      wc[k][0]=ww.x; wc[k][1]=ww.y; wc[k][2]=ww.z; wc[k][3]=ww.w;
    }
    #pragma unroll
    for (int rep = 0; rep < 8; rep++){
      const int l = rep*32 + lsub;
      const float dtl = sDt[l];
      const float dte = sDte[l];
      // depthwise conv over global-time within batch
      float ca[8] = {0,0,0,0,0,0,0,0};
      const int tb = (r0 & 2047) + l;       // t within batch
      #pragma unroll
      for (int j = 0; j < 4; j++){
        if (tb - 3 + j >= 0){
          const bfrag8 px = *(const bfrag8*)(projb + (size_t)(r0 + l - 3 + j)*NPAD + DI + h*64 + p0);
          #pragma unroll
          for (int k = 0; k < 8; k++) ca[k] += b2f((uint16_t)px[k]) * wc[k][j];
        }
      }
      const bfrag8 vb = *(const bfrag8*)(projb + (size_t)(r0 + l)*NPAD + 8192 + h*64 + p0);
      const int usrc = l >> 3;
      const int lrem = l & 7;
      #pragma unroll
      for (int k = 0; k < 8; k++){
        const int p = p0 + k;
        const int phys = usrc ^ (p & 7) ^ (p >> 3);
        const float xv = ca[k] / (1.f + __expf(-ca[k]));   // SiLU
        sXT[p*256 + phys*8 + lrem] = f2b(xv * dtl);
        sBT[p*256 + phys*8 + lrem] = f2b(b2f((uint16_t)vb[k]) * dte);
      }
    }
  }
  __syncthreads();

  const int i0 = wave * 64;                 // this wave's i-strip
  facc4 yacc[4][4] = {};

  #pragma unroll 1
  for (int jt = 0; jt < 8; jt++){
    // S'[j,i] = B @ C^T  (swapped so repack is contiguous b64 writes)
    facc4 sacc[2][4] = {};
    #pragma unroll
    for (int ks = 0; ks < 2; ks++){
      bfrag8 aB[2], bC[4];
      #pragma unroll
      for (int jf = 0; jf < 2; jf++){
        const int j = jt*32 + jf*16 + (lane & 15);
        const int u = ks*4 + (lane >> 4);
        aB[jf] = *(const bfrag8*)(sBc + j*64 + ((u ^ (j & 7)) << 3));
      }
      #pragma unroll
      for (int f = 0; f < 4; f++){
        const int i = i0 + f*16 + (lane & 15);
        const int u = ks*4 + (lane >> 4);
        bC[f] = *(const bfrag8*)(sCc + i*64 + ((u ^ (i & 7)) << 3));
      }
      #pragma unroll
      for (int jf = 0; jf < 2; jf++)
        #pragma unroll
        for (int f = 0; f < 4; f++)
          sacc[jf][f] = __builtin_amdgcn_mfma_f32_16x16x32_bf16(aB[jf], bC[f], sacc[jf][f], 0, 0, 0);
    }
    // decay*SCALE, causal mask, pack bf16 -> per-wave S strip [i][j]
    #pragma unroll
    for (int jf = 0; jf < 2; jf++)
      #pragma unroll
      for (int f = 0; f < 4; f++){
        const int iloc = f*16 + (lane & 15);
        const float cumi = sCum[i0 + iloc];
        uint64_t pk = 0;
        #pragma unroll
        for (int r = 0; r < 4; r++){
          const int j = jt*32 + jf*16 + (lane >> 4)*4 + r;
          float v = 0.f;
          if (j <= i0 + iloc)
            v = sacc[jf][f][r] * SCALEF * __expf(cumi - sCum[j]);
          pk |= ((uint64_t)f2b(v)) << (16*r);
        }
        const int jl = jf*16 + (lane >> 4)*4;
        const int phys2 = (jl >> 3) ^ (iloc & 3);
        *(uint64_t*)(&sS[wave][iloc*32 + phys2*8 + (jl & 7)]) = pk;
      }
    // y_intra += S_strip @ xdt   (A from strip, B from sXT)
    bfrag8 bX[4];
    #pragma unroll
    for (int pf = 0; pf < 4; pf++){
      const int p = pf*16 + (lane & 15);
      const int u = jt*4 + (lane >> 4);
      bX[pf] = *(const bfrag8*)(sXT + p*256 + ((u ^ (p & 7) ^ (p >> 3)) << 3));
    }
    #pragma unroll
    for (int f = 0; f < 4; f++){
      const int iloc = f*16 + (lane & 15);
      const int phys2 = (lane >> 4) ^ (iloc & 3);
      const bfrag8 aS = *(const bfrag8*)(&sS[wave][iloc*32 + phys2*8]);
      #pragma unroll
      for (int pf = 0; pf < 4; pf++)
        yacc[f][pf] = __builtin_amdgcn_mfma_f32_16x16x32_bf16(aS, bX[pf], yacc[f][pf], 0, 0, 0);
    }
  }

  // delta_h[p,n] = sum_l (xconv*dt)[l,p] * (B*dte)[l,n]; wave owns p-strip wave*16
  facc4 dacc[4] = {};
  #pragma unroll
  for (int ks = 0; ks < 8; ks++){
    const int p = wave*16 + (lane & 15);
    const int u = ks*4 + (lane >> 4);
    const bfrag8 aX = *(const bfrag8*)(sXT + p*256 + ((u ^ (p & 7) ^ (p >> 3)) << 3));
    #pragma unroll
    for (int nf = 0; nf < 4; nf++){
      const int n = nf*16 + (lane & 15);
      const bfrag8 bB = *(const bfrag8*)(sBT + n*256 + ((u ^ (n & 7) ^ (n >> 3)) << 3));
      dacc[nf] = __builtin_amdgcn_mfma_f32_16x16x32_bf16(aX, bB, dacc[nf], 0, 0, 0);
    }
  }

  #pragma unroll
  for (int f = 0; f < 4; f++)
    #pragma unroll
    for (int pf = 0; pf < 4; pf++)
      #pragma unroll
      for (int r = 0; r < 4; r++){
        const int i = i0 + f*16 + (lane >> 4)*4 + r;
        const int p = pf*16 + (lane & 15);
        yvb[(size_t)(r0 + i)*DI + h*64 + p] = f2b(yacc[f][pf][r]);
      }
  #pragma unroll
  for (int nf = 0; nf < 4; nf++)
    #pragma unroll
    for (int r = 0; r < 4; r++){
      const int p = wave*16 + (lane >> 4)*4 + r;
      const int n = nf*16 + (lane & 15);
      dh[(size_t)bx*4096 + p*64 + n] = dacc[nf][r];
    }
}

// ---------------------------------------------------------------- cross-chunk state scan (8 steps)
__global__ __launch_bounds__(256) void scan_states(
    const float* __restrict__ dh, const float* __restrict__ ctotb, float* __restrict__ states)
{
  const int bh = blockIdx.x;                // b*64 + h
  const int b = bh >> 6, h = bh & 63;
  const int tid = threadIdx.x;
  float st[16];
  #pragma unroll
  for (int k = 0; k < 16; k++) st[k] = 0.f;
  for (int c = 0; c < 8; c++){
    const int g = (b*8 + c)*64 + h;
    const size_t base = (size_t)g * 4096;
    const float cd = __expf(ctotb[g]);
    #pragma unroll
    for (int k = 0; k < 4; k++){
      const int e = tid*4 + k*1024;
      float4 o; o.x = st[k*4]; o.y = st[k*4+1]; o.z = st[k*4+2]; o.w = st[k*4+3];
      *(float4*)(states + base + e) = o;    // state BEFORE chunk c
      const float4 d = *(const float4*)(dh + base + e);
      st[k*4]   = cd*st[k*4]   + d.x;
      st[k*4+1] = cd*st[k*4+1] + d.y;
      st[k*4+2] = cd*st[k*4+2] + d.z;
      st[k*4+3] = cd*st[k*4+3] + d.w;
    }
  }
}

// ---------------------------------------------------------------- pass2: y += exp(cum)*SCALE * C @ h^T  (bf16 RMW)
__global__ __launch_bounds__(256) void chunk_pass2(
    const uint16_t* __restrict__ projb, const float* __restrict__ states,
    const float* __restrict__ cumb, uint16_t* __restrict__ yvb)
{
  __shared__ __align__(16) uint16_t sCc[256*64];
  __shared__ __align__(16) uint16_t sH[64*64];    // [p][n] swz
  __shared__ float sCum[256];
  const int tid = threadIdx.x, lane = tid & 63, wave = tid >> 6;
  const int bx = blockIdx.x, h = bx & 63, r0 = (bx >> 6) << 8;
  {
    const int Ccol = 12288 + h*64;
    const int sr = lane >> 3;
    const int lu = (lane & 7) ^ (sr & 7);
    const uint16_t* cS = projb + (size_t)(r0 + wave*64 + sr)*NPAD + Ccol + lu*8;
    uint16_t* cD = sCc + wave*4096;
    #pragma unroll
    for (int i = 0; i < 8; i++) gload_lds16(cS + (size_t)(i*8)*NPAD, cD + i*512);
  }
  #pragma unroll
  for (int k = 0; k < 4; k++){
    const int e = tid*4 + k*1024;
    const float4 v = *(const float4*)(states + (size_t)bx*4096 + e);
    const int p = e >> 6, n0 = e & 63;
    const int phys = (n0 >> 3) ^ (p & 7);
    uint64_t pk = (uint64_t)f2b(v.x) | ((uint64_t)f2b(v.y) << 16)
                | ((uint64_t)f2b(v.z) << 32) | ((uint64_t)f2b(v.w) << 48);
    *(uint64_t*)(&sH[p*64 + phys*8 + (n0 & 7)]) = pk;
  }
  sCum[tid] = cumb[bx*256 + tid];
  __syncthreads();

  const int i0 = wave*64;
  facc4 acc[4][4] = {};
  #pragma unroll
  for (int ks = 0; ks < 2; ks++){
    bfrag8 aC[4], bH[4];
    #pragma unroll
    for (int f = 0; f < 4; f++){
      const int i = i0 + f*16 + (lane & 15);
      const int u = ks*4 + (lane >> 4);
      aC[f] = *(const bfrag8*)(sCc + i*64 + ((u ^ (i & 7)) << 3));
    }
    #pragma unroll
    for (int pf = 0; pf < 4; pf++){
      const int p = pf*16 + (lane & 15);
      const int u = ks*4 + (lane >> 4);
      bH[pf] = *(const bfrag8*)(sH + p*64 + ((u ^ (p & 7)) << 3));
    }
    #pragma unroll
    for (int f = 0; f < 4; f++)
      #pragma unroll
      for (int pf = 0; pf < 4; pf++)
        acc[f][pf] = __builtin_amdgcn_mfma_f32_16x16x32_bf16(aC[f], bH[pf], acc[f][pf], 0, 0, 0);
  }
  #pragma unroll
  for (int f = 0; f < 4; f++)
    #pragma unroll
    for (int r = 0; r < 4; r++){
      const int i = i0 + f*16 + (lane >> 4)*4 + r;
      const float sc = SCALEF * __expf(sCum[i]);
      #pragma unroll
      for (int pf = 0; pf < 4; pf++){
        const int p = pf*16 + (lane & 15);
        uint16_t* yp = yvb + (size_t)(r0 + i)*DI + h*64 + p;
        *yp = f2b(b2f(*yp) + acc[f][pf][r] * sc);
      }
    }
}

// ---------------------------------------------------------------- RMSNorm + SiLU(z) gate -> bf16
__global__ __launch_bounds__(256) void norm_gate(
    const uint16_t* __restrict__ yvb, const uint16_t* __restrict__ projb, uint16_t* __restrict__ yb)
{
  const int row = blockIdx.x, tid = threadIdx.x;
  float v[16];
  float ss = 0.f;
  #pragma unroll
  for (int k = 0; k < 2; k++){
    const bfrag8 y8 = *(const bfrag8*)(yvb + (size_t)row*DI + tid*8 + k*2048);
    #pragma unroll
    for (int j = 0; j < 8; j++){
      const float f = b2f((uint16_t)y8[j]);
      v[k*8+j] = f;
      ss += f*f;
    }
  }
  #pragma unroll
  for (int off = 32; off > 0; off >>= 1) ss += __shfl_down(ss, off);
  __shared__ float red[4];
  if ((tid & 63) == 0) red[tid >> 6] = ss;
  __syncthreads();
  const float inv = rsqrtf((red[0]+red[1]+red[2]+red[3]) * (1.f/4096.f) + 1.1920929e-07f);
  #pragma unroll
  for (int k = 0; k < 2; k++){
    const int e = tid*8 + k*2048;
    const bfrag8 z8 = *(const bfrag8*)(projb + (size_t)row*NPAD + e);
    uint16_t o[8];
    #pragma unroll
    for (int j = 0; j < 8; j++){
      const float z = b2f((uint16_t)z8[j]);
      const float g = z / (1.f + __expf(-z));
      o[j] = f2b(v[k*8+j] * inv * g);
    }
    uint4 pk;
    pk.x = (uint32_t)o[0] | ((uint32_t)o[1] << 16);
    pk.y = (uint32_t)o[2] | ((uint32_t)o[3] << 16);
    pk.z = (uint32_t)o[4] | ((uint32_t)o[5] << 16);
    pk.w = (uint32_t)o[6] | ((uint32_t)o[7] << 16);
    *(uint4*)(yb + (size_t)row*DI + e) = pk;
  }
}

// ---------------------------------------------------------------- launcher
extern "C" void kernel_launch(void* const* d_in, const int* in_sizes, int n_in,
                              void* d_out, int out_size, void* d_ws, size_t ws_size,
                              hipStream_t stream)
{
  (void)in_sizes; (void)n_in; (void)out_size; (void)ws_size;
  const float* x         = (const float*)d_in[0];
  const float* in_proj_w = (const float*)d_in[1];
  const float* conv_w    = (const float*)d_in[2];
  const float* A_log     = (const float*)d_in[3];
  const float* dt_bias   = (const float*)d_in[4];
  const float* out_proj_w= (const float*)d_in[5];
  float* out = (float*)d_out;

  char* ws = (char*)d_ws;
  uint16_t* xb    = (uint16_t*)(ws + 0);               // 4096x2048 bf16 = 16.8MB (dead after gemm1)
  uint16_t* yvb   = (uint16_t*)(ws + 0);               // 4096x4096 bf16 = 33.5MB (overlaps xb + wb head)
  uint16_t* wb    = (uint16_t*)(ws + 16777216);        // 16640x2048 bf16 -> end 84,934,656 (dead after gemm1)
  uint16_t* projb = (uint16_t*)(ws + 84934656);        // 4096x16640 bf16 -> end 221,249,536
  float* dtraw    = (float*)(ws + 221249536);          // 4096x64 f32
  float* dtb      = (float*)(ws + 222298112);          // 1024x256 f32
  float* cumb     = (float*)(ws + 223346688);          // 1024x256 f32
  float* ctotb    = (float*)(ws + 224395264);          // 1024 f32
  uint16_t* yb    = (uint16_t*)(ws + 224399360);       // 4096x4096 bf16 -> 257,953,792
  float* dh       = (float*)(ws + 257953792);          // 1024x64x64 f32 -> 274,731,008
  float* states   = (float*)(ws + 274731008);          // 1024x64x64 f32 -> 291,508,224
  uint16_t* opb   = (uint16_t*)(ws + 291508224);       // 2048x4096 bf16 -> 308,285,440

  // casts
  cast_f32_to_bf16<<<8192, 256, 0, stream>>>(x, xb, 2097152);
  cast_f32_to_bf16<<<32896, 256, 0, stream>>>(in_proj_w, wb, 8421376);
  hipMemsetAsync(wb + (size_t)16448*2048, 0, (size_t)192*2048*2, stream);   // zero pad rows of W
  cast_f32_to_bf16<<<8192, 256, 0, stream>>>(out_proj_w, opb, 2097152);

  // in_proj GEMM (bf16 out + f32 dtraw side-channel): 4-phase counted-vmcnt + panel map
  gemm_bt7<<<1040, 512, 0, stream>>>(xb, wb, projb, dtraw);

  dt_cum<<<256, 256, 0, stream>>>(dtraw, A_log, dt_bias, dtb, cumb, ctotb);
  chunk_pass1<<<1024, 256, 0, stream>>>(projb, conv_w, dtb, cumb, ctotb, yvb, dh);
  scan_states<<<128, 256, 0, stream>>>(dh, ctotb, states);
  chunk_pass2<<<1024, 256, 0, stream>>>(projb, states, cumb, yvb);
  norm_gate<<<4096, 256, 0, stream>>>(yvb, projb, yb);

  // out_proj GEMM: 128x128 tiles, 32 mt x 16 nt = 512 blocks, 2 blocks/CU, direct f32 out
  gemm97<<<512, 256, 0, stream>>>(yb, opb, out, 2048, 4096, 16);
}

// Round 11
// 600.092 us; speedup vs baseline: 2.0313x; 1.0143x over previous
//
#include <hip/hip_runtime.h>
#include <cstdint>
#include <cstddef>

// ---------------------------------------------------------------- types/helpers
typedef __attribute__((ext_vector_type(8))) short bfrag8;   // 8 bf16 = 4 VGPR (MFMA A/B frag)
typedef __attribute__((ext_vector_type(4))) float facc4;    // MFMA C/D frag

#define DEV static __device__ __forceinline__

DEV uint16_t f2b(float f){                       // f32 -> bf16, RNE
  uint32_t b = __builtin_bit_cast(uint32_t, f);
  return (uint16_t)((b + 0x7FFFu + ((b >> 16) & 1u)) >> 16);
}
DEV float b2f(uint16_t h){
  uint32_t b = ((uint32_t)h) << 16;
  return __builtin_bit_cast(float, b);
}
DEV void gload_lds16(const void* g, void* l){    // async global->LDS, 16B/lane
  __builtin_amdgcn_global_load_lds((const __attribute__((address_space(1))) unsigned int*)g,
                                   (__attribute__((address_space(3))) unsigned int*)l, 16, 0, 0);
}

#define NPAD   16640      // 65*256 padded proj width (16448 real)
#define DI     4096
#define SCALEF 0.125f     // D_STATE^-0.5

// ---------------------------------------------------------------- fused cast: x, in_proj_w, out_proj_w -> bf16
// one launch instead of three (saves launch/tail overhead)
__global__ __launch_bounds__(256) void cast3(
    const float* __restrict__ x, const float* __restrict__ w, const float* __restrict__ op,
    uint16_t* __restrict__ xb, uint16_t* __restrict__ wb, uint16_t* __restrict__ opb)
{
  const int i = blockIdx.x * 256 + threadIdx.x;
  const float* src; uint16_t* dst; int j;
  if (i < 2097152){ src = x; dst = xb; j = i; }
  else if (i < 10518528){ src = w; dst = wb; j = i - 2097152; }
  else if (i < 12615680){ src = op; dst = opb; j = i - 10518528; }
  else return;
  const float4 v = ((const float4*)src)[j];
  uint64_t q = (uint64_t)f2b(v.x) | ((uint64_t)f2b(v.y) << 16)
             | ((uint64_t)f2b(v.z) << 32) | ((uint64_t)f2b(v.w) << 48);
  ((uint64_t*)dst)[j] = q;
}

// ---------------------------------------------------------------- GEMM1: proj = x @ W^T, reg-dbuf pipeline
// BM=BN=256, BK=64, 8 waves (2M x 4N), per-wave 128x64 C. 2 LDS buffers (128KB).
// PANEL-CHUNKED tile map (R8-proven, -40us): 13 panels x (16 mt x 5 nt), XCD-swizzled within panel.
// bf16 out (ld=NPAD) + f32 dtraw side-channel cols[16384,16448).
__global__ __launch_bounds__(512, 2) void gemm_bt5(
    const uint16_t* __restrict__ A, const uint16_t* __restrict__ Bw,
    uint16_t* __restrict__ Cout, float* __restrict__ dtraw)
{
  __shared__ __align__(16) uint16_t sA[2][256*64];
  __shared__ __align__(16) uint16_t sB[2][256*64];
  const int tid = threadIdx.x, lane = tid & 63, wave = tid >> 6;
  // panel map: bid in [0,1040): pid = bid/80, r = bid%80, XCD-swizzle r over 80 (80%8==0)
  const int bid = blockIdx.x;
  const int pid = bid / 80;
  const int r = bid - pid * 80;
  const int rs = (r & 7) * 10 + (r >> 3);
  const int mt = rs / 5;
  const int nt = pid * 5 + (rs - mt * 5);
  const int m0 = mt << 8, n0 = nt << 8;
  const int Krow = 2048, NT = 32;
  const int wm = wave >> 2, wn = wave & 3;

  // staging: per call, all 8 waves fill 64 rows (wave*8 + lane>>3); lane unit (lane&7),
  // source unit pre-swizzled (lane&7)^(lane>>3) so phys u holds logical u^(row&7).
  const int sr = lane >> 3;
  const int slu = ((lane & 7) ^ sr) << 3;
  const uint16_t* aS = A  + (size_t)(m0 + wave*8 + sr) * Krow + slu;
  const uint16_t* bS = Bw + (size_t)(n0 + wave*8 + sr) * Krow + slu;

  // frag-read constants: logical unit u at phys u^(row&7)
  const int l15 = lane & 15;
  const int q = lane >> 4;
  const int u0 = ((q)     ^ (l15 & 7)) << 3;
  const int u1 = ((q + 4) ^ (l15 & 7)) << 3;
  const int abase = (wm*128 + l15) << 6;       // + mi*1024 (mi 0..7)
  const int bbase = (wn*64  + l15) << 6;       // + ni*1024

  facc4 acc[8][4] = {};
  bfrag8 a0[8], b0[4], a1[8], b1[4];

#define STA(bs, tt, c) gload_lds16(aS + (size_t)((c)*64)*Krow + (tt)*64, &sA[bs][((c)*64 + wave*8) << 6])
#define STB(bs, tt, c) gload_lds16(bS + (size_t)((c)*64)*Krow + (tt)*64, &sB[bs][((c)*64 + wave*8) << 6])
#define STAGE8(bs, tt) do{ STB(bs,tt,0);STB(bs,tt,1);STB(bs,tt,2);STB(bs,tt,3); \
                           STA(bs,tt,0);STA(bs,tt,1);STA(bs,tt,2);STA(bs,tt,3); }while(0)

  STAGE8(0, 0);
  asm volatile("s_waitcnt vmcnt(0)" ::: "memory");
  asm volatile("s_barrier" ::: "memory");
  __builtin_amdgcn_sched_barrier(0);
  #pragma unroll
  for (int i = 0; i < 8; i++) a0[i] = *(const bfrag8*)&sA[0][abase + i*1024 + u0];
  #pragma unroll
  for (int i = 0; i < 4; i++) b0[i] = *(const bfrag8*)&sB[0][bbase + i*1024 + u0];

  #pragma unroll 1
  for (int t = 0; t < NT; ++t){
    const int c = t & 1;
    const bool st = (t + 1 < NT);
    const uint16_t* sa = sA[c];
    const uint16_t* sb = sB[c];
    if (st){ STAGE8(c ^ 1, t + 1); }
    #pragma unroll
    for (int i = 0; i < 8; i++) a1[i] = *(const bfrag8*)&sa[abase + i*1024 + u1];
    #pragma unroll
    for (int i = 0; i < 4; i++) b1[i] = *(const bfrag8*)&sb[bbase + i*1024 + u1];
    __builtin_amdgcn_sched_barrier(0);
    __builtin_amdgcn_s_setprio(1);
    #pragma unroll
    for (int mi = 0; mi < 8; mi++)
      #pragma unroll
      for (int ni = 0; ni < 4; ni++)
        acc[mi][ni] = __builtin_amdgcn_mfma_f32_16x16x32_bf16(a0[mi], b0[ni], acc[mi][ni], 0, 0, 0);
    __builtin_amdgcn_s_setprio(0);
    __builtin_amdgcn_sched_barrier(0);
    asm volatile("s_waitcnt lgkmcnt(0)" ::: "memory");
    if (st){
      asm volatile("s_waitcnt vmcnt(0)" ::: "memory");
      asm volatile("s_barrier" ::: "memory");
    }
    __builtin_amdgcn_sched_barrier(0);
    if (st){
      const uint16_t* na = sA[c ^ 1];
      const uint16_t* nb = sB[c ^ 1];
      #pragma unroll
      for (int i = 0; i < 8; i++) a0[i] = *(const bfrag8*)&na[abase + i*1024 + u0];
      #pragma unroll
      for (int i = 0; i < 4; i++) b0[i] = *(const bfrag8*)&nb[bbase + i*1024 + u0];
    }
    __builtin_amdgcn_sched_barrier(0);
    __builtin_amdgcn_s_setprio(1);
    #pragma unroll
    for (int mi = 0; mi < 8; mi++)
      #pragma unroll
      for (int ni = 0; ni < 4; ni++)
        acc[mi][ni] = __builtin_amdgcn_mfma_f32_16x16x32_bf16(a1[mi], b1[ni], acc[mi][ni], 0, 0, 0);
    __builtin_amdgcn_s_setprio(0);
    __builtin_amdgcn_sched_barrier(0);
  }
#undef STA
#undef STB
#undef STAGE8

  #pragma unroll
  for (int mi = 0; mi < 8; mi++)
    #pragma unroll
    for (int ni = 0; ni < 4; ni++)
      #pragma unroll
      for (int r2 = 0; r2 < 4; r2++){
        const int gm = m0 + wm*128 + mi*16 + (lane >> 4)*4 + r2;
        const int gn = n0 + wn*64 + ni*16 + l15;
        const float v = acc[mi][ni][r2];
        Cout[(size_t)gm * NPAD + gn] = f2b(v);
        if (gn >= 16384 && gn < 16448) dtraw[gm*64 + (gn - 16384)] = v;
      }
}

// ---------------------------------------------------------------- GEMM2: m97-class 128x128, 2 blocks/CU (f32 out)
// NEW (R11): nt-major XCD map — XCD x owns nt in {x*npx .. x*npx+npx-1} (B panel 2MB -> L2-resident
// per XCD; B re-reads from L2 not L3). idx>>? : nt = xcd*npx + idx%npx, mt = idx/npx.
// Cuts L3 staged traffic from ~1.07GB (mt-major) to ~0.3-0.5GB.
__global__ __launch_bounds__(256, 2) void gemm97(
    const uint16_t* __restrict__ A, const uint16_t* __restrict__ Bw,
    float* __restrict__ Cout, int Ndim, int Krow, int ntiles)
{
  __shared__ __align__(16) uint16_t sA[2][128*64];
  __shared__ __align__(16) uint16_t sB[2][128*64];
  const int tid = threadIdx.x, lane = tid & 63, wave = tid >> 6;
  const int bid = blockIdx.x;
  const int npx = ntiles >> 3;              // n-tiles per XCD (ntiles % 8 == 0)
  const int xcd = bid & 7;
  const int idx = bid >> 3;
  const int nt = xcd * npx + (idx % npx);
  const int mt = idx / npx;
  const int m0 = mt << 7, n0 = nt << 7;
  const int wm = wave >> 1, wn = wave & 1;
  const int NT = Krow >> 6;

  const int sr = lane >> 3;
  const int slu = ((lane & 7) ^ sr) << 3;
  const uint16_t* aS = A  + (size_t)(m0 + wave*8 + sr) * Krow + slu;
  const uint16_t* bS = Bw + (size_t)(n0 + wave*8 + sr) * Krow + slu;

  const int l15 = lane & 15;
  const int q = lane >> 4;
  const int u0 = ((q)     ^ (l15 & 7)) << 3;
  const int u1 = ((q + 4) ^ (l15 & 7)) << 3;
  const int abase = (wm*64 + l15) << 6;     // + mi*1024
  const int bbase = (wn*64 + l15) << 6;     // + ni*1024

  facc4 acc[4][4] = {};

#define GA(bs, tt, c) gload_lds16(aS + (size_t)((c)*32)*Krow + (tt)*64, &sA[bs][((c)*32 + wave*8) << 6])
#define GB(bs, tt, c) gload_lds16(bS + (size_t)((c)*32)*Krow + (tt)*64, &sB[bs][((c)*32 + wave*8) << 6])
#define STAGE(bs, tt) do{ GA(bs,tt,0);GA(bs,tt,1);GA(bs,tt,2);GA(bs,tt,3); \
                          GB(bs,tt,0);GB(bs,tt,1);GB(bs,tt,2);GB(bs,tt,3); }while(0)

  STAGE(0, 0);
  asm volatile("s_waitcnt vmcnt(0)" ::: "memory");
  asm volatile("s_barrier" ::: "memory");
  __builtin_amdgcn_sched_barrier(0);

  #pragma unroll 1
  for (int t = 0; t < NT; ++t){
    const int c = t & 1;
    const bool st = (t + 1 < NT);
    const uint16_t* sa = sA[c];
    const uint16_t* sb = sB[c];
    if (st){ STAGE(c ^ 1, t + 1); }
    bfrag8 af[2][4], bf[2][4];
    #pragma unroll
    for (int mi = 0; mi < 4; mi++){
      af[0][mi] = *(const bfrag8*)&sa[abase + mi*1024 + u0];
      af[1][mi] = *(const bfrag8*)&sa[abase + mi*1024 + u1];
    }
    #pragma unroll
    for (int ni = 0; ni < 4; ni++){
      bf[0][ni] = *(const bfrag8*)&sb[bbase + ni*1024 + u0];
      bf[1][ni] = *(const bfrag8*)&sb[bbase + ni*1024 + u1];
    }
    __builtin_amdgcn_sched_barrier(0);
    __builtin_amdgcn_s_setprio(1);
    #pragma unroll
    for (int ks = 0; ks < 2; ks++)
      #pragma unroll
      for (int mi = 0; mi < 4; mi++)
        #pragma unroll
        for (int ni = 0; ni < 4; ni++)
          acc[mi][ni] = __builtin_amdgcn_mfma_f32_16x16x32_bf16(af[ks][mi], bf[ks][ni], acc[mi][ni], 0, 0, 0);
    __builtin_amdgcn_s_setprio(0);
    __builtin_amdgcn_sched_barrier(0);
    if (st){
      asm volatile("s_waitcnt vmcnt(0)" ::: "memory");
      asm volatile("s_barrier" ::: "memory");
      __builtin_amdgcn_sched_barrier(0);
    }
  }
#undef GA
#undef GB
#undef STAGE

  #pragma unroll
  for (int mi = 0; mi < 4; mi++)
    #pragma unroll
    for (int ni = 0; ni < 4; ni++)
      #pragma unroll
      for (int r = 0; r < 4; r++){
        const int gm = m0 + wm*64 + mi*16 + (lane >> 4)*4 + r;
        const int gn = n0 + wn*64 + ni*16 + l15;
        Cout[(size_t)gm * Ndim + gn] = acc[mi][ni][r];
      }
}

// ---------------------------------------------------------------- dt = clip(softplus(dtraw+bias)), cumsum(A*dt)
__global__ __launch_bounds__(256) void dt_cum(
    const float* __restrict__ dtraw, const float* __restrict__ A_log, const float* __restrict__ dt_bias,
    float* __restrict__ dtb, float* __restrict__ cumb, float* __restrict__ ctotb)
{
  const int g = blockIdx.x*4 + (threadIdx.x >> 6);   // (b*8+c)*64+h
  const int lane = threadIdx.x & 63;
  const int h = g & 63;
  const int r0 = (g >> 6) << 8;
  const float A = -__expf(A_log[h]);
  const float bias = dt_bias[h];
  float loc[4], s = 0.f;
  #pragma unroll
  for (int k = 0; k < 4; k++){
    const int l = lane*4 + k;
    const float xr = dtraw[(size_t)(r0 + l)*64 + h] + bias;
    const float sp = (xr > 20.f) ? xr : log1pf(__expf(xr));
    const float dt = fminf(fmaxf(sp, 1e-4f), 0.5f);
    dtb[g*256 + l] = dt;
    s += A * dt;
    loc[k] = s;
  }
  float run = s;
  #pragma unroll
  for (int off = 1; off < 64; off <<= 1){
    const float tmp = __shfl_up(run, off);
    if (lane >= off) run += tmp;
  }
  const float excl = run - s;
  #pragma unroll
  for (int k = 0; k < 4; k++) cumb[g*256 + lane*4 + k] = excl + loc[k];
  if (lane == 63) ctotb[g] = run;
}

// ---------------------------------------------------------------- pass1: per (b,c,h) conv+SiLU fused, y_intra + delta_h
__global__ __launch_bounds__(256) void chunk_pass1(
    const uint16_t* __restrict__ projb, const float* __restrict__ conv_w,
    const float* __restrict__ dtb, const float* __restrict__ cumb,
    const float* __restrict__ ctotb, uint16_t* __restrict__ yvb, float* __restrict__ dh)
{
  __shared__ __align__(16) uint16_t sCc[256*64];   // C tile, [l][n] XOR-swz
  __shared__ __align__(16) uint16_t sBc[256*64];   // B tile, [l][n] XOR-swz
  __shared__ __align__(16) uint16_t sXT[64*256];   // (xconv*dt)^T  [p][l] swz u^(p&7)^(p>>3)
  __shared__ __align__(16) uint16_t sBT[64*256];   // (B*dte)^T  [n][l] same swz
  __shared__ __align__(16) uint16_t sS[4][64*32];  // per-wave S strip [i][j] swz
  __shared__ float sCum[256];
  __shared__ float sDt[256];
  __shared__ float sDte[256];

  const int tid = threadIdx.x, lane = tid & 63, wave = tid >> 6;
  const int bx = blockIdx.x;                // ((b*8+c)*64 + h)
  const int h = bx & 63;
  const int r0 = (bx >> 6) << 8;            // global row base b*2048 + c*256

  // stage Cc/Bc via global_load_lds, source-swizzled
  {
    const int Ccol = 12288 + h*64;
    const int Bcol = 8192 + h*64;
    const int sr = lane >> 3;
    const int lu = (lane & 7) ^ (sr & 7);
    const uint16_t* cS = projb + (size_t)(r0 + wave*64 + sr)*NPAD + Ccol + lu*8;
    const uint16_t* bS = projb + (size_t)(r0 + wave*64 + sr)*NPAD + Bcol + lu*8;
    uint16_t* cD = sCc + wave*4096;
    uint16_t* bD = sBc + wave*4096;
    #pragma unroll
    for (int i = 0; i < 8; i++){
      gload_lds16(cS + (size_t)(i*8)*NPAD, cD + i*512);
      gload_lds16(bS + (size_t)(i*8)*NPAD, bD + i*512);
    }
  }
  const float ctot = ctotb[bx];
  {
    const float cv = cumb[bx*256 + tid];
    sCum[tid] = cv;
    sDt[tid]  = dtb[bx*256 + tid];
    sDte[tid] = __expf(ctot - cv);          // decay_to_end
  }
  __syncthreads();

  // reg-scatter transposed tiles; x comes from fused depthwise conv(4)+SiLU
  {
    const int lsub = tid >> 3;              // 0..31
    const int p0 = (tid & 7) * 8;
    float wc[8][4];
    #pragma unroll
    for (int k = 0; k < 8; k++){
      const float4 ww = *(const float4*)(conv_w + (size_t)(h*64 + p0 + k)*4);
      wc[k][0]=ww.x; wc[k][1]=ww.y; wc[k][2]=ww.z; wc[k][3]=ww.w;
    }
    #pragma unroll
    for (int rep = 0; rep < 8; rep++){
      const int l = rep*32 + lsub;
      const float dtl = sDt[l];
      const float dte = sDte[l];
      // depthwise conv over global-time within batch
      float ca[8] = {0,0,0,0,0,0,0,0};
      const int tb = (r0 & 2047) + l;       // t within batch
      #pragma unroll
      for (int j = 0; j < 4; j++){
        if (tb - 3 + j >= 0){
          const bfrag8 px = *(const bfrag8*)(projb + (size_t)(r0 + l - 3 + j)*NPAD + DI + h*64 + p0);
          #pragma unroll
          for (int k = 0; k < 8; k++) ca[k] += b2f((uint16_t)px[k]) * wc[k][j];
        }
      }
      const bfrag8 vb = *(const bfrag8*)(projb + (size_t)(r0 + l)*NPAD + 8192 + h*64 + p0);
      const int usrc = l >> 3;
      const int lrem = l & 7;
      #pragma unroll
      for (int k = 0; k < 8; k++){
        const int p = p0 + k;
        const int phys = usrc ^ (p & 7) ^ (p >> 3);
        const float xv = ca[k] / (1.f + __expf(-ca[k]));   // SiLU
        sXT[p*256 + phys*8 + lrem] = f2b(xv * dtl);
        sBT[p*256 + phys*8 + lrem] = f2b(b2f((uint16_t)vb[k]) * dte);
      }
    }
  }
  __syncthreads();

  const int i0 = wave * 64;                 // this wave's i-strip
  facc4 yacc[4][4] = {};

  #pragma unroll 1
  for (int jt = 0; jt < 8; jt++){
    // S'[j,i] = B @ C^T  (swapped so repack is contiguous b64 writes)
    facc4 sacc[2][4] = {};
    #pragma unroll
    for (int ks = 0; ks < 2; ks++){
      bfrag8 aB[2], bC[4];
      #pragma unroll
      for (int jf = 0; jf < 2; jf++){
        const int j = jt*32 + jf*16 + (lane & 15);
        const int u = ks*4 + (lane >> 4);
        aB[jf] = *(const bfrag8*)(sBc + j*64 + ((u ^ (j & 7)) << 3));
      }
      #pragma unroll
      for (int f = 0; f < 4; f++){
        const int i = i0 + f*16 + (lane & 15);
        const int u = ks*4 + (lane >> 4);
        bC[f] = *(const bfrag8*)(sCc + i*64 + ((u ^ (i & 7)) << 3));
      }
      #pragma unroll
      for (int jf = 0; jf < 2; jf++)
        #pragma unroll
        for (int f = 0; f < 4; f++)
          sacc[jf][f] = __builtin_amdgcn_mfma_f32_16x16x32_bf16(aB[jf], bC[f], sacc[jf][f], 0, 0, 0);
    }
    // decay*SCALE, causal mask, pack bf16 -> per-wave S strip [i][j]
    #pragma unroll
    for (int jf = 0; jf < 2; jf++)
      #pragma unroll
      for (int f = 0; f < 4; f++){
        const int iloc = f*16 + (lane & 15);
        const float cumi = sCum[i0 + iloc];
        uint64_t pk = 0;
        #pragma unroll
        for (int r = 0; r < 4; r++){
          const int j = jt*32 + jf*16 + (lane >> 4)*4 + r;
          float v = 0.f;
          if (j <= i0 + iloc)
            v = sacc[jf][f][r] * SCALEF * __expf(cumi - sCum[j]);
          pk |= ((uint64_t)f2b(v)) << (16*r);
        }
        const int jl = jf*16 + (lane >> 4)*4;
        const int phys2 = (jl >> 3) ^ (iloc & 3);
        *(uint64_t*)(&sS[wave][iloc*32 + phys2*8 + (jl & 7)]) = pk;
      }
    // y_intra += S_strip @ xdt   (A from strip, B from sXT)
    bfrag8 bX[4];
    #pragma unroll
    for (int pf = 0; pf < 4; pf++){
      const int p = pf*16 + (lane & 15);
      const int u = jt*4 + (lane >> 4);
      bX[pf] = *(const bfrag8*)(sXT + p*256 + ((u ^ (p & 7) ^ (p >> 3)) << 3));
    }
    #pragma unroll
    for (int f = 0; f < 4; f++){
      const int iloc = f*16 + (lane & 15);
      const int phys2 = (lane >> 4) ^ (iloc & 3);
      const bfrag8 aS = *(const bfrag8*)(&sS[wave][iloc*32 + phys2*8]);
      #pragma unroll
      for (int pf = 0; pf < 4; pf++)
        yacc[f][pf] = __builtin_amdgcn_mfma_f32_16x16x32_bf16(aS, bX[pf], yacc[f][pf], 0, 0, 0);
    }
  }

  // delta_h[p,n] = sum_l (xconv*dt)[l,p] * (B*dte)[l,n]; wave owns p-strip wave*16
  facc4 dacc[4] = {};
  #pragma unroll
  for (int ks = 0; ks < 8; ks++){
    const int p = wave*16 + (lane & 15);
    const int u = ks*4 + (lane >> 4);
    const bfrag8 aX = *(const bfrag8*)(sXT + p*256 + ((u ^ (p & 7) ^ (p >> 3)) << 3));
    #pragma unroll
    for (int nf = 0; nf < 4; nf++){
      const int n = nf*16 + (lane & 15);
      const bfrag8 bB = *(const bfrag8*)(sBT + n*256 + ((u ^ (n & 7) ^ (n >> 3)) << 3));
      dacc[nf] = __builtin_amdgcn_mfma_f32_16x16x32_bf16(aX, bB, dacc[nf], 0, 0, 0);
    }
  }

  #pragma unroll
  for (int f = 0; f < 4; f++)
    #pragma unroll
    for (int pf = 0; pf < 4; pf++)
      #pragma unroll
      for (int r = 0; r < 4; r++){
        const int i = i0 + f*16 + (lane >> 4)*4 + r;
        const int p = pf*16 + (lane & 15);
        yvb[(size_t)(r0 + i)*DI + h*64 + p] = f2b(yacc[f][pf][r]);
      }
  #pragma unroll
  for (int nf = 0; nf < 4; nf++)
    #pragma unroll
    for (int r = 0; r < 4; r++){
      const int p = wave*16 + (lane >> 4)*4 + r;
      const int n = nf*16 + (lane & 15);
      dh[(size_t)bx*4096 + p*64 + n] = dacc[nf][r];
    }
}

// ---------------------------------------------------------------- cross-chunk state scan (8 steps)
__global__ __launch_bounds__(256) void scan_states(
    const float* __restrict__ dh, const float* __restrict__ ctotb, float* __restrict__ states)
{
  const int bh = blockIdx.x;                // b*64 + h
  const int b = bh >> 6, h = bh & 63;
  const int tid = threadIdx.x;
  float st[16];
  #pragma unroll
  for (int k = 0; k < 16; k++) st[k] = 0.f;
  for (int c = 0; c < 8; c++){
    const int g = (b*8 + c)*64 + h;
    const size_t base = (size_t)g * 4096;
    const float cd = __expf(ctotb[g]);
    #pragma unroll
    for (int k = 0; k < 4; k++){
      const int e = tid*4 + k*1024;
      float4 o; o.x = st[k*4]; o.y = st[k*4+1]; o.z = st[k*4+2]; o.w = st[k*4+3];
      *(float4*)(states + base + e) = o;    // state BEFORE chunk c
      const float4 d = *(const float4*)(dh + base + e);
      st[k*4]   = cd*st[k*4]   + d.x;
      st[k*4+1] = cd*st[k*4+1] + d.y;
      st[k*4+2] = cd*st[k*4+2] + d.z;
      st[k*4+3] = cd*st[k*4+3] + d.w;
    }
  }
}

// ---------------------------------------------------------------- pass2: y += exp(cum)*SCALE * C @ h^T  (bf16 RMW)
__global__ __launch_bounds__(256) void chunk_pass2(
    const uint16_t* __restrict__ projb, const float* __restrict__ states,
    const float* __restrict__ cumb, uint16_t* __restrict__ yvb)
{
  __shared__ __align__(16) uint16_t sCc[256*64];
  __shared__ __align__(16) uint16_t sH[64*64];    // [p][n] swz
  __shared__ float sCum[256];
  const int tid = threadIdx.x, lane = tid & 63, wave = tid >> 6;
  const int bx = blockIdx.x, h = bx & 63, r0 = (bx >> 6) << 8;
  {
    const int Ccol = 12288 + h*64;
    const int sr = lane >> 3;
    const int lu = (lane & 7) ^ (sr & 7);
    const uint16_t* cS = projb + (size_t)(r0 + wave*64 + sr)*NPAD + Ccol + lu*8;
    uint16_t* cD = sCc + wave*4096;
    #pragma unroll
    for (int i = 0; i < 8; i++) gload_lds16(cS + (size_t)(i*8)*NPAD, cD + i*512);
  }
  #pragma unroll
  for (int k = 0; k < 4; k++){
    const int e = tid*4 + k*1024;
    const float4 v = *(const float4*)(states + (size_t)bx*4096 + e);
    const int p = e >> 6, n0 = e & 63;
    const int phys = (n0 >> 3) ^ (p & 7);
    uint64_t pk = (uint64_t)f2b(v.x) | ((uint64_t)f2b(v.y) << 16)
                | ((uint64_t)f2b(v.z) << 32) | ((uint64_t)f2b(v.w) << 48);
    *(uint64_t*)(&sH[p*64 + phys*8 + (n0 & 7)]) = pk;
  }
  sCum[tid] = cumb[bx*256 + tid];
  __syncthreads();

  const int i0 = wave*64;
  facc4 acc[4][4] = {};
  #pragma unroll
  for (int ks = 0; ks < 2; ks++){
    bfrag8 aC[4], bH[4];
    #pragma unroll
    for (int f = 0; f < 4; f++){
      const int i = i0 + f*16 + (lane & 15);
      const int u = ks*4 + (lane >> 4);
      aC[f] = *(const bfrag8*)(sCc + i*64 + ((u ^ (i & 7)) << 3));
    }
    #pragma unroll
    for (int pf = 0; pf < 4; pf++){
      const int p = pf*16 + (lane & 15);
      const int u = ks*4 + (lane >> 4);
      bH[pf] = *(const bfrag8*)(sH + p*64 + ((u ^ (p & 7)) << 3));
    }
    #pragma unroll
    for (int f = 0; f < 4; f++)
      #pragma unroll
      for (int pf = 0; pf < 4; pf++)
        acc[f][pf] = __builtin_amdgcn_mfma_f32_16x16x32_bf16(aC[f], bH[pf], acc[f][pf], 0, 0, 0);
  }
  #pragma unroll
  for (int f = 0; f < 4; f++)
    #pragma unroll
    for (int r = 0; r < 4; r++){
      const int i = i0 + f*16 + (lane >> 4)*4 + r;
      const float sc = SCALEF * __expf(sCum[i]);
      #pragma unroll
      for (int pf = 0; pf < 4; pf++){
        const int p = pf*16 + (lane & 15);
        uint16_t* yp = yvb + (size_t)(r0 + i)*DI + h*64 + p;
        *yp = f2b(b2f(*yp) + acc[f][pf][r] * sc);
      }
    }
}

// ---------------------------------------------------------------- RMSNorm + SiLU(z) gate -> bf16
__global__ __launch_bounds__(256) void norm_gate(
    const uint16_t* __restrict__ yvb, const uint16_t* __restrict__ projb, uint16_t* __restrict__ yb)
{
  const int row = blockIdx.x, tid = threadIdx.x;
  float v[16];
  float ss = 0.f;
  #pragma unroll
  for (int k = 0; k < 2; k++){
    const bfrag8 y8 = *(const bfrag8*)(yvb + (size_t)row*DI + tid*8 + k*2048);
    #pragma unroll
    for (int j = 0; j < 8; j++){
      const float f = b2f((uint16_t)y8[j]);
      v[k*8+j] = f;
      ss += f*f;
    }
  }
  #pragma unroll
  for (int off = 32; off > 0; off >>= 1) ss += __shfl_down(ss, off);
  __shared__ float red[4];
  if ((tid & 63) == 0) red[tid >> 6] = ss;
  __syncthreads();
  const float inv = rsqrtf((red[0]+red[1]+red[2]+red[3]) * (1.f/4096.f) + 1.1920929e-07f);
  #pragma unroll
  for (int k = 0; k < 2; k++){
    const int e = tid*8 + k*2048;
    const bfrag8 z8 = *(const bfrag8*)(projb + (size_t)row*NPAD + e);
    uint16_t o[8];
    #pragma unroll
    for (int j = 0; j < 8; j++){
      const float z = b2f((uint16_t)z8[j]);
      const float g = z / (1.f + __expf(-z));
      o[j] = f2b(v[k*8+j] * inv * g);
    }
    uint4 pk;
    pk.x = (uint32_t)o[0] | ((uint32_t)o[1] << 16);
    pk.y = (uint32_t)o[2] | ((uint32_t)o[3] << 16);
    pk.z = (uint32_t)o[4] | ((uint32_t)o[5] << 16);
    pk.w = (uint32_t)o[6] | ((uint32_t)o[7] << 16);
    *(uint4*)(yb + (size_t)row*DI + e) = pk;
  }
}

// ---------------------------------------------------------------- launcher
extern "C" void kernel_launch(void* const* d_in, const int* in_sizes, int n_in,
                              void* d_out, int out_size, void* d_ws, size_t ws_size,
                              hipStream_t stream)
{
  (void)in_sizes; (void)n_in; (void)out_size; (void)ws_size;
  const float* x         = (const float*)d_in[0];
  const float* in_proj_w = (const float*)d_in[1];
  const float* conv_w    = (const float*)d_in[2];
  const float* A_log     = (const float*)d_in[3];
  const float* dt_bias   = (const float*)d_in[4];
  const float* out_proj_w= (const float*)d_in[5];
  float* out = (float*)d_out;

  char* ws = (char*)d_ws;
  uint16_t* xb    = (uint16_t*)(ws + 0);               // 4096x2048 bf16 = 16.8MB (dead after gemm1)
  uint16_t* yvb   = (uint16_t*)(ws + 0);               // 4096x4096 bf16 = 33.5MB (overlaps xb + wb head)
  uint16_t* wb    = (uint16_t*)(ws + 16777216);        // 16640x2048 bf16 -> end 84,934,656 (dead after gemm1)
  uint16_t* projb = (uint16_t*)(ws + 84934656);        // 4096x16640 bf16 -> end 221,249,536
  float* dtraw    = (float*)(ws + 221249536);          // 4096x64 f32
  float* dtb      = (float*)(ws + 222298112);          // 1024x256 f32
  float* cumb     = (float*)(ws + 223346688);          // 1024x256 f32
  float* ctotb    = (float*)(ws + 224395264);          // 1024 f32
  uint16_t* yb    = (uint16_t*)(ws + 224399360);       // 4096x4096 bf16 -> 257,953,792
  float* dh       = (float*)(ws + 257953792);          // 1024x64x64 f32 -> 274,731,008
  float* states   = (float*)(ws + 274731008);          // 1024x64x64 f32 -> 291,508,224
  uint16_t* opb   = (uint16_t*)(ws + 291508224);       // 2048x4096 bf16 -> 308,285,440

  // fused casts (x, in_proj_w, out_proj_w) + pad-zero
  cast3<<<49280, 256, 0, stream>>>(x, in_proj_w, out_proj_w, xb, wb, opb);
  hipMemsetAsync(wb + (size_t)16448*2048, 0, (size_t)192*2048*2, stream);   // zero pad rows of W

  // in_proj GEMM (bf16 out + f32 dtraw side-channel): panel-chunked 13 x (16mt x 5nt)
  gemm_bt5<<<1040, 512, 0, stream>>>(xb, wb, projb, dtraw);

  dt_cum<<<256, 256, 0, stream>>>(dtraw, A_log, dt_bias, dtb, cumb, ctotb);
  chunk_pass1<<<1024, 256, 0, stream>>>(projb, conv_w, dtb, cumb, ctotb, yvb, dh);
  scan_states<<<128, 256, 0, stream>>>(dh, ctotb, states);
  chunk_pass2<<<1024, 256, 0, stream>>>(projb, states, cumb, yvb);
  norm_gate<<<4096, 256, 0, stream>>>(yvb, projb, yb);

  // out_proj GEMM: 128x128 tiles, nt-major XCD map (B panel L2-resident per XCD), 512 blocks, 2/CU
  gemm97<<<512, 256, 0, stream>>>(yb, opb, out, 2048, 4096, 16);
}

// Round 12
// 597.613 us; speedup vs baseline: 2.0398x; 1.0041x over previous
//
#include <hip/hip_runtime.h>
#include <cstdint>
#include <cstddef>

// ---------------------------------------------------------------- types/helpers
typedef __attribute__((ext_vector_type(8))) short bfrag8;   // 8 bf16 = 4 VGPR (MFMA A/B frag)
typedef __attribute__((ext_vector_type(4))) float facc4;    // MFMA C/D frag

#define DEV static __device__ __forceinline__

DEV uint16_t f2b(float f){                       // f32 -> bf16, RNE
  uint32_t b = __builtin_bit_cast(uint32_t, f);
  return (uint16_t)((b + 0x7FFFu + ((b >> 16) & 1u)) >> 16);
}
DEV float b2f(uint16_t h){
  uint32_t b = ((uint32_t)h) << 16;
  return __builtin_bit_cast(float, b);
}
DEV void gload_lds16(const void* g, void* l){    // async global->LDS, 16B/lane
  __builtin_amdgcn_global_load_lds((const __attribute__((address_space(1))) unsigned int*)g,
                                   (__attribute__((address_space(3))) unsigned int*)l, 16, 0, 0);
}

#define NPAD   16640      // 65*256 padded proj width (16448 real)
#define DI     4096
#define SCALEF 0.125f     // D_STATE^-0.5

// ---------------------------------------------------------------- fused cast: x, in_proj_w, out_proj_w -> bf16
__global__ __launch_bounds__(256) void cast3(
    const float* __restrict__ x, const float* __restrict__ w, const float* __restrict__ op,
    uint16_t* __restrict__ xb, uint16_t* __restrict__ wb, uint16_t* __restrict__ opb)
{
  const int i = blockIdx.x * 256 + threadIdx.x;
  const float* src; uint16_t* dst; int j;
  if (i < 2097152){ src = x; dst = xb; j = i; }
  else if (i < 10518528){ src = w; dst = wb; j = i - 2097152; }
  else if (i < 12615680){ src = op; dst = opb; j = i - 10518528; }
  else return;
  const float4 v = ((const float4*)src)[j];
  uint64_t q = (uint64_t)f2b(v.x) | ((uint64_t)f2b(v.y) << 16)
             | ((uint64_t)f2b(v.z) << 32) | ((uint64_t)f2b(v.w) << 48);
  ((uint64_t*)dst)[j] = q;
}

// ---------------------------------------------------------------- GEMM1: proj = x @ W^T, reg-dbuf pipeline
// BM=BN=256, BK=64, 8 waves (2M x 4N), per-wave 128x64 C. 2 LDS buffers (128KB).
// PANEL-CHUNKED tile map (R8-proven): 13 panels x (16 mt x 5 nt), XCD-swizzled within panel.
// bf16 out (ld=NPAD) + f32 dtraw side-channel cols[16384,16448).
__global__ __launch_bounds__(512, 2) void gemm_bt5(
    const uint16_t* __restrict__ A, const uint16_t* __restrict__ Bw,
    uint16_t* __restrict__ Cout, float* __restrict__ dtraw)
{
  __shared__ __align__(16) uint16_t sA[2][256*64];
  __shared__ __align__(16) uint16_t sB[2][256*64];
  const int tid = threadIdx.x, lane = tid & 63, wave = tid >> 6;
  // panel map: bid in [0,1040): pid = bid/80, r = bid%80, XCD-swizzle r over 80 (80%8==0)
  const int bid = blockIdx.x;
  const int pid = bid / 80;
  const int r = bid - pid * 80;
  const int rs = (r & 7) * 10 + (r >> 3);
  const int mt = rs / 5;
  const int nt = pid * 5 + (rs - mt * 5);
  const int m0 = mt << 8, n0 = nt << 8;
  const int Krow = 2048, NT = 32;
  const int wm = wave >> 2, wn = wave & 3;

  const int sr = lane >> 3;
  const int slu = ((lane & 7) ^ sr) << 3;
  const uint16_t* aS = A  + (size_t)(m0 + wave*8 + sr) * Krow + slu;
  const uint16_t* bS = Bw + (size_t)(n0 + wave*8 + sr) * Krow + slu;

  const int l15 = lane & 15;
  const int q = lane >> 4;
  const int u0 = ((q)     ^ (l15 & 7)) << 3;
  const int u1 = ((q + 4) ^ (l15 & 7)) << 3;
  const int abase = (wm*128 + l15) << 6;       // + mi*1024 (mi 0..7)
  const int bbase = (wn*64  + l15) << 6;       // + ni*1024

  facc4 acc[8][4] = {};
  bfrag8 a0[8], b0[4], a1[8], b1[4];

#define STA(bs, tt, c) gload_lds16(aS + (size_t)((c)*64)*Krow + (tt)*64, &sA[bs][((c)*64 + wave*8) << 6])
#define STB(bs, tt, c) gload_lds16(bS + (size_t)((c)*64)*Krow + (tt)*64, &sB[bs][((c)*64 + wave*8) << 6])
#define STAGE8(bs, tt) do{ STB(bs,tt,0);STB(bs,tt,1);STB(bs,tt,2);STB(bs,tt,3); \
                           STA(bs,tt,0);STA(bs,tt,1);STA(bs,tt,2);STA(bs,tt,3); }while(0)

  STAGE8(0, 0);
  asm volatile("s_waitcnt vmcnt(0)" ::: "memory");
  asm volatile("s_barrier" ::: "memory");
  __builtin_amdgcn_sched_barrier(0);
  #pragma unroll
  for (int i = 0; i < 8; i++) a0[i] = *(const bfrag8*)&sA[0][abase + i*1024 + u0];
  #pragma unroll
  for (int i = 0; i < 4; i++) b0[i] = *(const bfrag8*)&sB[0][bbase + i*1024 + u0];

  #pragma unroll 1
  for (int t = 0; t < NT; ++t){
    const int c = t & 1;
    const bool st = (t + 1 < NT);
    const uint16_t* sa = sA[c];
    const uint16_t* sb = sB[c];
    if (st){ STAGE8(c ^ 1, t + 1); }
    #pragma unroll
    for (int i = 0; i < 8; i++) a1[i] = *(const bfrag8*)&sa[abase + i*1024 + u1];
    #pragma unroll
    for (int i = 0; i < 4; i++) b1[i] = *(const bfrag8*)&sb[bbase + i*1024 + u1];
    __builtin_amdgcn_sched_barrier(0);
    __builtin_amdgcn_s_setprio(1);
    #pragma unroll
    for (int mi = 0; mi < 8; mi++)
      #pragma unroll
      for (int ni = 0; ni < 4; ni++)
        acc[mi][ni] = __builtin_amdgcn_mfma_f32_16x16x32_bf16(a0[mi], b0[ni], acc[mi][ni], 0, 0, 0);
    __builtin_amdgcn_s_setprio(0);
    __builtin_amdgcn_sched_barrier(0);
    asm volatile("s_waitcnt lgkmcnt(0)" ::: "memory");
    if (st){
      asm volatile("s_waitcnt vmcnt(0)" ::: "memory");
      asm volatile("s_barrier" ::: "memory");
    }
    __builtin_amdgcn_sched_barrier(0);
    if (st){
      const uint16_t* na = sA[c ^ 1];
      const uint16_t* nb = sB[c ^ 1];
      #pragma unroll
      for (int i = 0; i < 8; i++) a0[i] = *(const bfrag8*)&na[abase + i*1024 + u0];
      #pragma unroll
      for (int i = 0; i < 4; i++) b0[i] = *(const bfrag8*)&nb[bbase + i*1024 + u0];
    }
    __builtin_amdgcn_sched_barrier(0);
    __builtin_amdgcn_s_setprio(1);
    #pragma unroll
    for (int mi = 0; mi < 8; mi++)
      #pragma unroll
      for (int ni = 0; ni < 4; ni++)
        acc[mi][ni] = __builtin_amdgcn_mfma_f32_16x16x32_bf16(a1[mi], b1[ni], acc[mi][ni], 0, 0, 0);
    __builtin_amdgcn_s_setprio(0);
    __builtin_amdgcn_sched_barrier(0);
  }
#undef STA
#undef STB
#undef STAGE8

  #pragma unroll
  for (int mi = 0; mi < 8; mi++)
    #pragma unroll
    for (int ni = 0; ni < 4; ni++)
      #pragma unroll
      for (int r2 = 0; r2 < 4; r2++){
        const int gm = m0 + wm*128 + mi*16 + (lane >> 4)*4 + r2;
        const int gn = n0 + wn*64 + ni*16 + l15;
        const float v = acc[mi][ni][r2];
        Cout[(size_t)gm * NPAD + gn] = f2b(v);
        if (gn >= 16384 && gn < 16448) dtraw[gm*64 + (gn - 16384)] = v;
      }
}

// ---------------------------------------------------------------- GEMM2: m97-class 128x128, 2 blocks/CU (f32 out)
// NEW (R12): 2D XCD-SQUARE map — each XCD owns an 8mt x 8nt super-tile; its 64 co-resident
// blocks touch only 256KB unique operand bytes per K-step -> L2-resident; 16x read
// amplification absorbed by L2 instead of L3 (1.07GB -> ~200MB L3 traffic).
// Bijective: mt=(xcd&3)*8+(idx&7), nt=(xcd>>2)*8+(idx>>3); xcd=bid&7 (round-robin dispatch).
__global__ __launch_bounds__(256, 2) void gemm97(
    const uint16_t* __restrict__ A, const uint16_t* __restrict__ Bw,
    float* __restrict__ Cout, int Ndim, int Krow)
{
  __shared__ __align__(16) uint16_t sA[2][128*64];
  __shared__ __align__(16) uint16_t sB[2][128*64];
  const int tid = threadIdx.x, lane = tid & 63, wave = tid >> 6;
  const int bid = blockIdx.x;
  const int xcd = bid & 7;
  const int idx = bid >> 3;                 // [0,64)
  const int mt = ((xcd & 3) << 3) + (idx & 7);
  const int nt = ((xcd >> 2) << 3) + (idx >> 3);
  const int m0 = mt << 7, n0 = nt << 7;
  const int wm = wave >> 1, wn = wave & 1;
  const int NT = Krow >> 6;

  const int sr = lane >> 3;
  const int slu = ((lane & 7) ^ sr) << 3;
  const uint16_t* aS = A  + (size_t)(m0 + wave*8 + sr) * Krow + slu;
  const uint16_t* bS = Bw + (size_t)(n0 + wave*8 + sr) * Krow + slu;

  const int l15 = lane & 15;
  const int q = lane >> 4;
  const int u0 = ((q)     ^ (l15 & 7)) << 3;
  const int u1 = ((q + 4) ^ (l15 & 7)) << 3;
  const int abase = (wm*64 + l15) << 6;     // + mi*1024
  const int bbase = (wn*64 + l15) << 6;     // + ni*1024

  facc4 acc[4][4] = {};

#define GA(bs, tt, c) gload_lds16(aS + (size_t)((c)*32)*Krow + (tt)*64, &sA[bs][((c)*32 + wave*8) << 6])
#define GB(bs, tt, c) gload_lds16(bS + (size_t)((c)*32)*Krow + (tt)*64, &sB[bs][((c)*32 + wave*8) << 6])
#define STAGE(bs, tt) do{ GA(bs,tt,0);GA(bs,tt,1);GA(bs,tt,2);GA(bs,tt,3); \
                          GB(bs,tt,0);GB(bs,tt,1);GB(bs,tt,2);GB(bs,tt,3); }while(0)

  STAGE(0, 0);
  asm volatile("s_waitcnt vmcnt(0)" ::: "memory");
  asm volatile("s_barrier" ::: "memory");
  __builtin_amdgcn_sched_barrier(0);

  #pragma unroll 1
  for (int t = 0; t < NT; ++t){
    const int c = t & 1;
    const bool st = (t + 1 < NT);
    const uint16_t* sa = sA[c];
    const uint16_t* sb = sB[c];
    if (st){ STAGE(c ^ 1, t + 1); }
    bfrag8 af[2][4], bf[2][4];
    #pragma unroll
    for (int mi = 0; mi < 4; mi++){
      af[0][mi] = *(const bfrag8*)&sa[abase + mi*1024 + u0];
      af[1][mi] = *(const bfrag8*)&sa[abase + mi*1024 + u1];
    }
    #pragma unroll
    for (int ni = 0; ni < 4; ni++){
      bf[0][ni] = *(const bfrag8*)&sb[bbase + ni*1024 + u0];
      bf[1][ni] = *(const bfrag8*)&sb[bbase + ni*1024 + u1];
    }
    __builtin_amdgcn_sched_barrier(0);
    __builtin_amdgcn_s_setprio(1);
    #pragma unroll
    for (int ks = 0; ks < 2; ks++)
      #pragma unroll
      for (int mi = 0; mi < 4; mi++)
        #pragma unroll
        for (int ni = 0; ni < 4; ni++)
          acc[mi][ni] = __builtin_amdgcn_mfma_f32_16x16x32_bf16(af[ks][mi], bf[ks][ni], acc[mi][ni], 0, 0, 0);
    __builtin_amdgcn_s_setprio(0);
    __builtin_amdgcn_sched_barrier(0);
    if (st){
      asm volatile("s_waitcnt vmcnt(0)" ::: "memory");
      asm volatile("s_barrier" ::: "memory");
      __builtin_amdgcn_sched_barrier(0);
    }
  }
#undef GA
#undef GB
#undef STAGE

  #pragma unroll
  for (int mi = 0; mi < 4; mi++)
    #pragma unroll
    for (int ni = 0; ni < 4; ni++)
      #pragma unroll
      for (int r = 0; r < 4; r++){
        const int gm = m0 + wm*64 + mi*16 + (lane >> 4)*4 + r;
        const int gn = n0 + wn*64 + ni*16 + l15;
        Cout[(size_t)gm * Ndim + gn] = acc[mi][ni][r];
      }
}

// ---------------------------------------------------------------- dt = clip(softplus(dtraw+bias)), cumsum(A*dt)
__global__ __launch_bounds__(256) void dt_cum(
    const float* __restrict__ dtraw, const float* __restrict__ A_log, const float* __restrict__ dt_bias,
    float* __restrict__ dtb, float* __restrict__ cumb, float* __restrict__ ctotb)
{
  const int g = blockIdx.x*4 + (threadIdx.x >> 6);   // (b*8+c)*64+h
  const int lane = threadIdx.x & 63;
  const int h = g & 63;
  const int r0 = (g >> 6) << 8;
  const float A = -__expf(A_log[h]);
  const float bias = dt_bias[h];
  float loc[4], s = 0.f;
  #pragma unroll
  for (int k = 0; k < 4; k++){
    const int l = lane*4 + k;
    const float xr = dtraw[(size_t)(r0 + l)*64 + h] + bias;
    const float sp = (xr > 20.f) ? xr : log1pf(__expf(xr));
    const float dt = fminf(fmaxf(sp, 1e-4f), 0.5f);
    dtb[g*256 + l] = dt;
    s += A * dt;
    loc[k] = s;
  }
  float run = s;
  #pragma unroll
  for (int off = 1; off < 64; off <<= 1){
    const float tmp = __shfl_up(run, off);
    if (lane >= off) run += tmp;
  }
  const float excl = run - s;
  #pragma unroll
  for (int k = 0; k < 4; k++) cumb[g*256 + lane*4 + k] = excl + loc[k];
  if (lane == 63) ctotb[g] = run;
}

// ---------------------------------------------------------------- pass1: per (b,c,h) conv+SiLU fused, y_intra + delta_h
__global__ __launch_bounds__(256) void chunk_pass1(
    const uint16_t* __restrict__ projb, const float* __restrict__ conv_w,
    const float* __restrict__ dtb, const float* __restrict__ cumb,
    const float* __restrict__ ctotb, uint16_t* __restrict__ yvb, float* __restrict__ dh)
{
  __shared__ __align__(16) uint16_t sCc[256*64];   // C tile, [l][n] XOR-swz
  __shared__ __align__(16) uint16_t sBc[256*64];   // B tile, [l][n] XOR-swz
  __shared__ __align__(16) uint16_t sXT[64*256];   // (xconv*dt)^T  [p][l] swz u^(p&7)^(p>>3)
  __shared__ __align__(16) uint16_t sBT[64*256];   // (B*dte)^T  [n][l] same swz
  __shared__ __align__(16) uint16_t sS[4][64*32];  // per-wave S strip [i][j] swz
  __shared__ float sCum[256];
  __shared__ float sDt[256];
  __shared__ float sDte[256];

  const int tid = threadIdx.x, lane = tid & 63, wave = tid >> 6;
  const int bx = blockIdx.x;                // ((b*8+c)*64 + h)
  const int h = bx & 63;
  const int r0 = (bx >> 6) << 8;            // global row base b*2048 + c*256

  // stage Cc/Bc via global_load_lds, source-swizzled
  {
    const int Ccol = 12288 + h*64;
    const int Bcol = 8192 + h*64;
    const int sr = lane >> 3;
    const int lu = (lane & 7) ^ (sr & 7);
    const uint16_t* cS = projb + (size_t)(r0 + wave*64 + sr)*NPAD + Ccol + lu*8;
    const uint16_t* bS = projb + (size_t)(r0 + wave*64 + sr)*NPAD + Bcol + lu*8;
    uint16_t* cD = sCc + wave*4096;
    uint16_t* bD = sBc + wave*4096;
    #pragma unroll
    for (int i = 0; i < 8; i++){
      gload_lds16(cS + (size_t)(i*8)*NPAD, cD + i*512);
      gload_lds16(bS + (size_t)(i*8)*NPAD, bD + i*512);
    }
  }
  const float ctot = ctotb[bx];
  {
    const float cv = cumb[bx*256 + tid];
    sCum[tid] = cv;
    sDt[tid]  = dtb[bx*256 + tid];
    sDte[tid] = __expf(ctot - cv);          // decay_to_end
  }
  __syncthreads();

  // reg-scatter transposed tiles; x comes from fused depthwise conv(4)+SiLU
  {
    const int lsub = tid >> 3;              // 0..31
    const int p0 = (tid & 7) * 8;
    float wc[8][4];
    #pragma unroll
    for (int k = 0; k < 8; k++){
      const float4 ww = *(const float4*)(conv_w + (size_t)(h*64 + p0 + k)*4);
      wc[k][0]=ww.x; wc[k][1]=ww.y; wc[k][2]=ww.z; wc[k][3]=ww.w;
    }
    #pragma unroll
    for (int rep = 0; rep < 8; rep++){
      const int l = rep*32 + lsub;
      const float dtl = sDt[l];
      const float dte = sDte[l];
      // depthwise conv over global-time within batch
      float ca[8] = {0,0,0,0,0,0,0,0};
      const int tb = (r0 & 2047) + l;       // t within batch
      #pragma unroll
      for (int j = 0; j < 4; j++){
        if (tb - 3 + j >= 0){
          const bfrag8 px = *(const bfrag8*)(projb + (size_t)(r0 + l - 3 + j)*NPAD + DI + h*64 + p0);
          #pragma unroll
          for (int k = 0; k < 8; k++) ca[k] += b2f((uint16_t)px[k]) * wc[k][j];
        }
      }
      const bfrag8 vb = *(const bfrag8*)(projb + (size_t)(r0 + l)*NPAD + 8192 + h*64 + p0);
      const int usrc = l >> 3;
      const int lrem = l & 7;
      #pragma unroll
      for (int k = 0; k < 8; k++){
        const int p = p0 + k;
        const int phys = usrc ^ (p & 7) ^ (p >> 3);
        const float xv = ca[k] / (1.f + __expf(-ca[k]));   // SiLU
        sXT[p*256 + phys*8 + lrem] = f2b(xv * dtl);
        sBT[p*256 + phys*8 + lrem] = f2b(b2f((uint16_t)vb[k]) * dte);
      }
    }
  }
  __syncthreads();

  const int i0 = wave * 64;                 // this wave's i-strip
  facc4 yacc[4][4] = {};

  #pragma unroll 1
  for (int jt = 0; jt < 8; jt++){
    // S'[j,i] = B @ C^T  (swapped so repack is contiguous b64 writes)
    facc4 sacc[2][4] = {};
    #pragma unroll
    for (int ks = 0; ks < 2; ks++){
      bfrag8 aB[2], bC[4];
      #pragma unroll
      for (int jf = 0; jf < 2; jf++){
        const int j = jt*32 + jf*16 + (lane & 15);
        const int u = ks*4 + (lane >> 4);
        aB[jf] = *(const bfrag8*)(sBc + j*64 + ((u ^ (j & 7)) << 3));
      }
      #pragma unroll
      for (int f = 0; f < 4; f++){
        const int i = i0 + f*16 + (lane & 15);
        const int u = ks*4 + (lane >> 4);
        bC[f] = *(const bfrag8*)(sCc + i*64 + ((u ^ (i & 7)) << 3));
      }
      #pragma unroll
      for (int jf = 0; jf < 2; jf++)
        #pragma unroll
        for (int f = 0; f < 4; f++)
          sacc[jf][f] = __builtin_amdgcn_mfma_f32_16x16x32_bf16(aB[jf], bC[f], sacc[jf][f], 0, 0, 0);
    }
    // decay*SCALE, causal mask, pack bf16 -> per-wave S strip [i][j]
    #pragma unroll
    for (int jf = 0; jf < 2; jf++)
      #pragma unroll
      for (int f = 0; f < 4; f++){
        const int iloc = f*16 + (lane & 15);
        const float cumi = sCum[i0 + iloc];
        uint64_t pk = 0;
        #pragma unroll
        for (int r = 0; r < 4; r++){
          const int j = jt*32 + jf*16 + (lane >> 4)*4 + r;
          float v = 0.f;
          if (j <= i0 + iloc)
            v = sacc[jf][f][r] * SCALEF * __expf(cumi - sCum[j]);
          pk |= ((uint64_t)f2b(v)) << (16*r);
        }
        const int jl = jf*16 + (lane >> 4)*4;
        const int phys2 = (jl >> 3) ^ (iloc & 3);
        *(uint64_t*)(&sS[wave][iloc*32 + phys2*8 + (jl & 7)]) = pk;
      }
    // y_intra += S_strip @ xdt   (A from strip, B from sXT)
    bfrag8 bX[4];
    #pragma unroll
    for (int pf = 0; pf < 4; pf++){
      const int p = pf*16 + (lane & 15);
      const int u = jt*4 + (lane >> 4);
      bX[pf] = *(const bfrag8*)(sXT + p*256 + ((u ^ (p & 7) ^ (p >> 3)) << 3));
    }
    #pragma unroll
    for (int f = 0; f < 4; f++){
      const int iloc = f*16 + (lane & 15);
      const int phys2 = (lane >> 4) ^ (iloc & 3);
      const bfrag8 aS = *(const bfrag8*)(&sS[wave][iloc*32 + phys2*8]);
      #pragma unroll
      for (int pf = 0; pf < 4; pf++)
        yacc[f][pf] = __builtin_amdgcn_mfma_f32_16x16x32_bf16(aS, bX[pf], yacc[f][pf], 0, 0, 0);
    }
  }

  // delta_h[p,n] = sum_l (xconv*dt)[l,p] * (B*dte)[l,n]; wave owns p-strip wave*16
  facc4 dacc[4] = {};
  #pragma unroll
  for (int ks = 0; ks < 8; ks++){
    const int p = wave*16 + (lane & 15);
    const int u = ks*4 + (lane >> 4);
    const bfrag8 aX = *(const bfrag8*)(sXT + p*256 + ((u ^ (p & 7) ^ (p >> 3)) << 3));
    #pragma unroll
    for (int nf = 0; nf < 4; nf++){
      const int n = nf*16 + (lane & 15);
      const bfrag8 bB = *(const bfrag8*)(sBT + n*256 + ((u ^ (n & 7) ^ (n >> 3)) << 3));
      dacc[nf] = __builtin_amdgcn_mfma_f32_16x16x32_bf16(aX, bB, dacc[nf], 0, 0, 0);
    }
  }

  #pragma unroll
  for (int f = 0; f < 4; f++)
    #pragma unroll
    for (int pf = 0; pf < 4; pf++)
      #pragma unroll
      for (int r = 0; r < 4; r++){
        const int i = i0 + f*16 + (lane >> 4)*4 + r;
        const int p = pf*16 + (lane & 15);
        yvb[(size_t)(r0 + i)*DI + h*64 + p] = f2b(yacc[f][pf][r]);
      }
  #pragma unroll
  for (int nf = 0; nf < 4; nf++)
    #pragma unroll
    for (int r = 0; r < 4; r++){
      const int p = wave*16 + (lane >> 4)*4 + r;
      const int n = nf*16 + (lane & 15);
      dh[(size_t)bx*4096 + p*64 + n] = dacc[nf][r];
    }
}

// ---------------------------------------------------------------- cross-chunk state scan (8 steps)
__global__ __launch_bounds__(256) void scan_states(
    const float* __restrict__ dh, const float* __restrict__ ctotb, float* __restrict__ states)
{
  const int bh = blockIdx.x;                // b*64 + h
  const int b = bh >> 6, h = bh & 63;
  const int tid = threadIdx.x;
  float st[16];
  #pragma unroll
  for (int k = 0; k < 16; k++) st[k] = 0.f;
  for (int c = 0; c < 8; c++){
    const int g = (b*8 + c)*64 + h;
    const size_t base = (size_t)g * 4096;
    const float cd = __expf(ctotb[g]);
    #pragma unroll
    for (int k = 0; k < 4; k++){
      const int e = tid*4 + k*1024;
      float4 o; o.x = st[k*4]; o.y = st[k*4+1]; o.z = st[k*4+2]; o.w = st[k*4+3];
      *(float4*)(states + base + e) = o;    // state BEFORE chunk c
      const float4 d = *(const float4*)(dh + base + e);
      st[k*4]   = cd*st[k*4]   + d.x;
      st[k*4+1] = cd*st[k*4+1] + d.y;
      st[k*4+2] = cd*st[k*4+2] + d.z;
      st[k*4+3] = cd*st[k*4+3] + d.w;
    }
  }
}

// ---------------------------------------------------------------- pass2: y += exp(cum)*SCALE * C @ h^T  (bf16 RMW)
__global__ __launch_bounds__(256) void chunk_pass2(
    const uint16_t* __restrict__ projb, const float* __restrict__ states,
    const float* __restrict__ cumb, uint16_t* __restrict__ yvb)
{
  __shared__ __align__(16) uint16_t sCc[256*64];
  __shared__ __align__(16) uint16_t sH[64*64];    // [p][n] swz
  __shared__ float sCum[256];
  const int tid = threadIdx.x, lane = tid & 63, wave = tid >> 6;
  const int bx = blockIdx.x, h = bx & 63, r0 = (bx >> 6) << 8;
  {
    const int Ccol = 12288 + h*64;
    const int sr = lane >> 3;
    const int lu = (lane & 7) ^ (sr & 7);
    const uint16_t* cS = projb + (size_t)(r0 + wave*64 + sr)*NPAD + Ccol + lu*8;
    uint16_t* cD = sCc + wave*4096;
    #pragma unroll
    for (int i = 0; i < 8; i++) gload_lds16(cS + (size_t)(i*8)*NPAD, cD + i*512);
  }
  #pragma unroll
  for (int k = 0; k < 4; k++){
    const int e = tid*4 + k*1024;
    const float4 v = *(const float4*)(states + (size_t)bx*4096 + e);
    const int p = e >> 6, n0 = e & 63;
    const int phys = (n0 >> 3) ^ (p & 7);
    uint64_t pk = (uint64_t)f2b(v.x) | ((uint64_t)f2b(v.y) << 16)
                | ((uint64_t)f2b(v.z) << 32) | ((uint64_t)f2b(v.w) << 48);
    *(uint64_t*)(&sH[p*64 + phys*8 + (n0 & 7)]) = pk;
  }
  sCum[tid] = cumb[bx*256 + tid];
  __syncthreads();

  const int i0 = wave*64;
  facc4 acc[4][4] = {};
  #pragma unroll
  for (int ks = 0; ks < 2; ks++){
    bfrag8 aC[4], bH[4];
    #pragma unroll
    for (int f = 0; f < 4; f++){
      const int i = i0 + f*16 + (lane & 15);
      const int u = ks*4 + (lane >> 4);
      aC[f] = *(const bfrag8*)(sCc + i*64 + ((u ^ (i & 7)) << 3));
    }
    #pragma unroll
    for (int pf = 0; pf < 4; pf++){
      const int p = pf*16 + (lane & 15);
      const int u = ks*4 + (lane >> 4);
      bH[pf] = *(const bfrag8*)(sH + p*64 + ((u ^ (p & 7)) << 3));
    }
    #pragma unroll
    for (int f = 0; f < 4; f++)
      #pragma unroll
      for (int pf = 0; pf < 4; pf++)
        acc[f][pf] = __builtin_amdgcn_mfma_f32_16x16x32_bf16(aC[f], bH[pf], acc[f][pf], 0, 0, 0);
  }
  #pragma unroll
  for (int f = 0; f < 4; f++)
    #pragma unroll
    for (int r = 0; r < 4; r++){
      const int i = i0 + f*16 + (lane >> 4)*4 + r;
      const float sc = SCALEF * __expf(sCum[i]);
      #pragma unroll
      for (int pf = 0; pf < 4; pf++){
        const int p = pf*16 + (lane & 15);
        uint16_t* yp = yvb + (size_t)(r0 + i)*DI + h*64 + p;
        *yp = f2b(b2f(*yp) + acc[f][pf][r] * sc);
      }
    }
}

// ---------------------------------------------------------------- RMSNorm + SiLU(z) gate -> bf16
__global__ __launch_bounds__(256) void norm_gate(
    const uint16_t* __restrict__ yvb, const uint16_t* __restrict__ projb, uint16_t* __restrict__ yb)
{
  const int row = blockIdx.x, tid = threadIdx.x;
  float v[16];
  float ss = 0.f;
  #pragma unroll
  for (int k = 0; k < 2; k++){
    const bfrag8 y8 = *(const bfrag8*)(yvb + (size_t)row*DI + tid*8 + k*2048);
    #pragma unroll
    for (int j = 0; j < 8; j++){
      const float f = b2f((uint16_t)y8[j]);
      v[k*8+j] = f;
      ss += f*f;
    }
  }
  #pragma unroll
  for (int off = 32; off > 0; off >>= 1) ss += __shfl_down(ss, off);
  __shared__ float red[4];
  if ((tid & 63) == 0) red[tid >> 6] = ss;
  __syncthreads();
  const float inv = rsqrtf((red[0]+red[1]+red[2]+red[3]) * (1.f/4096.f) + 1.1920929e-07f);
  #pragma unroll
  for (int k = 0; k < 2; k++){
    const int e = tid*8 + k*2048;
    const bfrag8 z8 = *(const bfrag8*)(projb + (size_t)row*NPAD + e);
    uint16_t o[8];
    #pragma unroll
    for (int j = 0; j < 8; j++){
      const float z = b2f((uint16_t)z8[j]);
      const float g = z / (1.f + __expf(-z));
      o[j] = f2b(v[k*8+j] * inv * g);
    }
    uint4 pk;
    pk.x = (uint32_t)o[0] | ((uint32_t)o[1] << 16);
    pk.y = (uint32_t)o[2] | ((uint32_t)o[3] << 16);
    pk.z = (uint32_t)o[4] | ((uint32_t)o[5] << 16);
    pk.w = (uint32_t)o[6] | ((uint32_t)o[7] << 16);
    *(uint4*)(yb + (size_t)row*DI + e) = pk;
  }
}

// ---------------------------------------------------------------- launcher
extern "C" void kernel_launch(void* const* d_in, const int* in_sizes, int n_in,
                              void* d_out, int out_size, void* d_ws, size_t ws_size,
                              hipStream_t stream)
{
  (void)in_sizes; (void)n_in; (void)out_size; (void)ws_size;
  const float* x         = (const float*)d_in[0];
  const float* in_proj_w = (const float*)d_in[1];
  const float* conv_w    = (const float*)d_in[2];
  const float* A_log     = (const float*)d_in[3];
  const float* dt_bias   = (const float*)d_in[4];
  const float* out_proj_w= (const float*)d_in[5];
  float* out = (float*)d_out;

  char* ws = (char*)d_ws;
  uint16_t* xb    = (uint16_t*)(ws + 0);               // 4096x2048 bf16 = 16.8MB (dead after gemm1)
  uint16_t* yvb   = (uint16_t*)(ws + 0);               // 4096x4096 bf16 = 33.5MB (overlaps xb + wb head)
  uint16_t* wb    = (uint16_t*)(ws + 16777216);        // 16640x2048 bf16 -> end 84,934,656 (dead after gemm1)
  uint16_t* projb = (uint16_t*)(ws + 84934656);        // 4096x16640 bf16 -> end 221,249,536
  float* dtraw    = (float*)(ws + 221249536);          // 4096x64 f32
  float* dtb      = (float*)(ws + 222298112);          // 1024x256 f32
  float* cumb     = (float*)(ws + 223346688);          // 1024x256 f32
  float* ctotb    = (float*)(ws + 224395264);          // 1024 f32
  uint16_t* yb    = (uint16_t*)(ws + 224399360);       // 4096x4096 bf16 -> 257,953,792
  float* dh       = (float*)(ws + 257953792);          // 1024x64x64 f32 -> 274,731,008
  float* states   = (float*)(ws + 274731008);          // 1024x64x64 f32 -> 291,508,224
  uint16_t* opb   = (uint16_t*)(ws + 291508224);       // 2048x4096 bf16 -> 308,285,440

  // fused casts (x, in_proj_w, out_proj_w) + pad-zero
  cast3<<<49280, 256, 0, stream>>>(x, in_proj_w, out_proj_w, xb, wb, opb);
  hipMemsetAsync(wb + (size_t)16448*2048, 0, (size_t)192*2048*2, stream);   // zero pad rows of W

  // in_proj GEMM (bf16 out + f32 dtraw side-channel): panel-chunked 13 x (16mt x 5nt)
  gemm_bt5<<<1040, 512, 0, stream>>>(xb, wb, projb, dtraw);

  dt_cum<<<256, 256, 0, stream>>>(dtraw, A_log, dt_bias, dtb, cumb, ctotb);
  chunk_pass1<<<1024, 256, 0, stream>>>(projb, conv_w, dtb, cumb, ctotb, yvb, dh);
  scan_states<<<128, 256, 0, stream>>>(dh, ctotb, states);
  chunk_pass2<<<1024, 256, 0, stream>>>(projb, states, cumb, yvb);
  norm_gate<<<4096, 256, 0, stream>>>(yvb, projb, yb);

  // out_proj GEMM: 128x128 tiles, XCD-square map (8mt x 8nt per XCD, L2-resident K-slices), 512 blocks
  gemm97<<<512, 256, 0, stream>>>(yb, opb, out, 2048, 4096);
}

// Round 13
// 583.823 us; speedup vs baseline: 2.0879x; 1.0236x over previous
//
#include <hip/hip_runtime.h>
#include <cstdint>
#include <cstddef>

// ---------------------------------------------------------------- types/helpers
typedef __attribute__((ext_vector_type(8))) short bfrag8;   // 8 bf16 = 4 VGPR (MFMA A/B frag)
typedef __attribute__((ext_vector_type(4))) float facc4;    // MFMA C/D frag

#define DEV static __device__ __forceinline__

DEV uint16_t f2b(float f){                       // f32 -> bf16, RNE
  uint32_t b = __builtin_bit_cast(uint32_t, f);
  return (uint16_t)((b + 0x7FFFu + ((b >> 16) & 1u)) >> 16);
}
DEV float b2f(uint16_t h){
  uint32_t b = ((uint32_t)h) << 16;
  return __builtin_bit_cast(float, b);
}
DEV void gload_lds16(const void* g, void* l){    // async global->LDS, 16B/lane
  __builtin_amdgcn_global_load_lds((const __attribute__((address_space(1))) unsigned int*)g,
                                   (__attribute__((address_space(3))) unsigned int*)l, 16, 0, 0);
}

#define NPAD   16384      // proj width (z|xconv|B|C), power-of-2 ld; dt handled by gemm_dt
#define DI     4096
#define SCALEF 0.125f     // D_STATE^-0.5

// ---------------------------------------------------------------- fused cast: x, in_proj_w, out_proj_w -> bf16
__global__ __launch_bounds__(256) void cast3(
    const float* __restrict__ x, const float* __restrict__ w, const float* __restrict__ op,
    uint16_t* __restrict__ xb, uint16_t* __restrict__ wb, uint16_t* __restrict__ opb)
{
  const int i = blockIdx.x * 256 + threadIdx.x;
  const float* src; uint16_t* dst; int j;
  if (i < 2097152){ src = x; dst = xb; j = i; }
  else if (i < 10518528){ src = w; dst = wb; j = i - 2097152; }
  else if (i < 12615680){ src = op; dst = opb; j = i - 10518528; }
  else return;
  const float4 v = ((const float4*)src)[j];
  uint64_t q = (uint64_t)f2b(v.x) | ((uint64_t)f2b(v.y) << 16)
             | ((uint64_t)f2b(v.z) << 32) | ((uint64_t)f2b(v.w) << 48);
  ((uint64_t*)dst)[j] = q;
}

// ---------------------------------------------------------------- GEMM1: proj = x @ W^T (cols 0..16384)
// BM=BN=256, BK=64, 8 waves (2M x 4N), per-wave 128x64 C. 2 LDS buffers (128KB, 1 blk/CU).
// GRID = 1024 = exactly 4 generations of 256 CUs (R12 insight: 1040 blocks cost a 5th,
// 6%-utilized generation ~60us; dt columns split into gemm_dt).
// PANEL map: 16 panels x (16 mt x 4 nt); XCD-swizzle within 64-block panel.
__global__ __launch_bounds__(512, 2) void gemm_bt5(
    const uint16_t* __restrict__ A, const uint16_t* __restrict__ Bw,
    uint16_t* __restrict__ Cout)
{
  __shared__ __align__(16) uint16_t sA[2][256*64];
  __shared__ __align__(16) uint16_t sB[2][256*64];
  const int tid = threadIdx.x, lane = tid & 63, wave = tid >> 6;
  // panel map: bid in [0,1024): pid = bid>>6, r = bid&63, XCD-swizzle r (64%8==0)
  const int bid = blockIdx.x;
  const int pid = bid >> 6;
  const int r = bid & 63;
  const int rs = (r & 7) * 8 + (r >> 3);
  const int mt = rs >> 2;
  const int nt = (pid << 2) + (rs & 3);
  const int m0 = mt << 8, n0 = nt << 8;
  const int Krow = 2048, NT = 32;
  const int wm = wave >> 2, wn = wave & 3;

  // staging: per call, all 8 waves fill 64 rows (wave*8 + lane>>3); lane unit (lane&7),
  // source unit pre-swizzled (lane&7)^(lane>>3) so phys u holds logical u^(row&7).
  const int sr = lane >> 3;
  const int slu = ((lane & 7) ^ sr) << 3;
  const uint16_t* aS = A  + (size_t)(m0 + wave*8 + sr) * Krow + slu;
  const uint16_t* bS = Bw + (size_t)(n0 + wave*8 + sr) * Krow + slu;

  // frag-read constants: logical unit u at phys u^(row&7)
  const int l15 = lane & 15;
  const int q = lane >> 4;
  const int u0 = ((q)     ^ (l15 & 7)) << 3;
  const int u1 = ((q + 4) ^ (l15 & 7)) << 3;
  const int abase = (wm*128 + l15) << 6;       // + mi*1024 (mi 0..7)
  const int bbase = (wn*64  + l15) << 6;       // + ni*1024

  facc4 acc[8][4] = {};
  bfrag8 a0[8], b0[4], a1[8], b1[4];

#define STA(bs, tt, c) gload_lds16(aS + (size_t)((c)*64)*Krow + (tt)*64, &sA[bs][((c)*64 + wave*8) << 6])
#define STB(bs, tt, c) gload_lds16(bS + (size_t)((c)*64)*Krow + (tt)*64, &sB[bs][((c)*64 + wave*8) << 6])
#define STAGE8(bs, tt) do{ STB(bs,tt,0);STB(bs,tt,1);STB(bs,tt,2);STB(bs,tt,3); \
                           STA(bs,tt,0);STA(bs,tt,1);STA(bs,tt,2);STA(bs,tt,3); }while(0)

  STAGE8(0, 0);
  asm volatile("s_waitcnt vmcnt(0)" ::: "memory");
  asm volatile("s_barrier" ::: "memory");
  __builtin_amdgcn_sched_barrier(0);
  #pragma unroll
  for (int i = 0; i < 8; i++) a0[i] = *(const bfrag8*)&sA[0][abase + i*1024 + u0];
  #pragma unroll
  for (int i = 0; i < 4; i++) b0[i] = *(const bfrag8*)&sB[0][bbase + i*1024 + u0];

  #pragma unroll 1
  for (int t = 0; t < NT; ++t){
    const int c = t & 1;
    const bool st = (t + 1 < NT);
    const uint16_t* sa = sA[c];
    const uint16_t* sb = sB[c];
    if (st){ STAGE8(c ^ 1, t + 1); }
    #pragma unroll
    for (int i = 0; i < 8; i++) a1[i] = *(const bfrag8*)&sa[abase + i*1024 + u1];
    #pragma unroll
    for (int i = 0; i < 4; i++) b1[i] = *(const bfrag8*)&sb[bbase + i*1024 + u1];
    __builtin_amdgcn_sched_barrier(0);
    __builtin_amdgcn_s_setprio(1);
    #pragma unroll
    for (int mi = 0; mi < 8; mi++)
      #pragma unroll
      for (int ni = 0; ni < 4; ni++)
        acc[mi][ni] = __builtin_amdgcn_mfma_f32_16x16x32_bf16(a0[mi], b0[ni], acc[mi][ni], 0, 0, 0);
    __builtin_amdgcn_s_setprio(0);
    __builtin_amdgcn_sched_barrier(0);
    asm volatile("s_waitcnt lgkmcnt(0)" ::: "memory");
    if (st){
      asm volatile("s_waitcnt vmcnt(0)" ::: "memory");
      asm volatile("s_barrier" ::: "memory");
    }
    __builtin_amdgcn_sched_barrier(0);
    if (st){
      const uint16_t* na = sA[c ^ 1];
      const uint16_t* nb = sB[c ^ 1];
      #pragma unroll
      for (int i = 0; i < 8; i++) a0[i] = *(const bfrag8*)&na[abase + i*1024 + u0];
      #pragma unroll
      for (int i = 0; i < 4; i++) b0[i] = *(const bfrag8*)&nb[bbase + i*1024 + u0];
    }
    __builtin_amdgcn_sched_barrier(0);
    __builtin_amdgcn_s_setprio(1);
    #pragma unroll
    for (int mi = 0; mi < 8; mi++)
      #pragma unroll
      for (int ni = 0; ni < 4; ni++)
        acc[mi][ni] = __builtin_amdgcn_mfma_f32_16x16x32_bf16(a1[mi], b1[ni], acc[mi][ni], 0, 0, 0);
    __builtin_amdgcn_s_setprio(0);
    __builtin_amdgcn_sched_barrier(0);
  }
#undef STA
#undef STB
#undef STAGE8

  #pragma unroll
  for (int mi = 0; mi < 8; mi++)
    #pragma unroll
    for (int ni = 0; ni < 4; ni++)
      #pragma unroll
      for (int r2 = 0; r2 < 4; r2++){
        const int gm = m0 + wm*128 + mi*16 + (lane >> 4)*4 + r2;
        const int gn = n0 + wn*64 + ni*16 + l15;
        Cout[(size_t)gm * NPAD + gn] = f2b(acc[mi][ni][r2]);
      }
}

// ---------------------------------------------------------------- gemm_dt: dtraw = x @ Wdt^T (f32 out)
// Wdt = W rows [16384,16448). 128 blocks x 256 thr (4 waves); block = 32 rows x 64 h, K=2048.
// Single-buffered LDS (12KB), 32 K-tiles of 64. Wave: wm=wave>>1 (16-row half), wn=wave&1 (32-h half).
__global__ __launch_bounds__(256) void gemm_dt(
    const uint16_t* __restrict__ A, const uint16_t* __restrict__ Wdt, float* __restrict__ dtraw)
{
  __shared__ __align__(16) uint16_t sX[32*64];   // 4 KB
  __shared__ __align__(16) uint16_t sW[64*64];   // 8 KB
  const int tid = threadIdx.x, lane = tid & 63, wave = tid >> 6;
  const int m0 = blockIdx.x << 5;
  const int wm = wave >> 1, wn = wave & 1;
  const int Krow = 2048;

  const int sr = lane >> 3;                      // row within wave-call
  const int slu = ((lane & 7) ^ sr) << 3;        // pre-swizzled source unit
  // sX: one call = 4 waves x 8 rows = 32 rows. sW: two calls of 32 rows.
  const uint16_t* xS = A   + (size_t)(m0 + wave*8 + sr) * Krow + slu;
  const uint16_t* wS = Wdt + (size_t)(wave*8 + sr) * Krow + slu;

  const int l15 = lane & 15;
  const int q = lane >> 4;
  const int u0 = ((q)     ^ (l15 & 7)) << 3;
  const int u1 = ((q + 4) ^ (l15 & 7)) << 3;
  const int abase = (wm*16 + l15) << 6;
  const int bbase = (wn*32 + l15) << 6;          // + nf*1024

  facc4 acc[2] = {};

  #pragma unroll 1
  for (int t = 0; t < 32; ++t){
    gload_lds16(xS + t*64, &sX[(wave*8) << 6]);
    gload_lds16(wS + t*64, &sW[(wave*8) << 6]);
    gload_lds16(wS + (size_t)32*Krow + t*64, &sW[(32 + wave*8) << 6]);
    asm volatile("s_waitcnt vmcnt(0)" ::: "memory");
    asm volatile("s_barrier" ::: "memory");
    bfrag8 a0 = *(const bfrag8*)&sX[abase + u0];
    bfrag8 a1 = *(const bfrag8*)&sX[abase + u1];
    #pragma unroll
    for (int nf = 0; nf < 2; nf++){
      const bfrag8 b0 = *(const bfrag8*)&sW[bbase + nf*1024 + u0];
      const bfrag8 b1 = *(const bfrag8*)&sW[bbase + nf*1024 + u1];
      acc[nf] = __builtin_amdgcn_mfma_f32_16x16x32_bf16(a0, b0, acc[nf], 0, 0, 0);
      acc[nf] = __builtin_amdgcn_mfma_f32_16x16x32_bf16(a1, b1, acc[nf], 0, 0, 0);
    }
    asm volatile("s_waitcnt lgkmcnt(0)" ::: "memory");
    asm volatile("s_barrier" ::: "memory");
  }

  #pragma unroll
  for (int nf = 0; nf < 2; nf++)
    #pragma unroll
    for (int r = 0; r < 4; r++){
      const int gm = m0 + wm*16 + (lane >> 4)*4 + r;
      const int h = wn*32 + nf*16 + l15;
      dtraw[gm*64 + h] = acc[nf][r];
    }
}

// ---------------------------------------------------------------- GEMM2: m97-class 128x128, 2 blocks/CU (f32 out)
__global__ __launch_bounds__(256, 2) void gemm97(
    const uint16_t* __restrict__ A, const uint16_t* __restrict__ Bw,
    float* __restrict__ Cout, int Ndim, int Krow)
{
  __shared__ __align__(16) uint16_t sA[2][128*64];
  __shared__ __align__(16) uint16_t sB[2][128*64];
  const int tid = threadIdx.x, lane = tid & 63, wave = tid >> 6;
  const int bid = blockIdx.x;
  const int xcd = bid & 7;
  const int idx = bid >> 3;                 // [0,64)
  const int mt = ((xcd & 3) << 3) + (idx & 7);
  const int nt = ((xcd >> 2) << 3) + (idx >> 3);
  const int m0 = mt << 7, n0 = nt << 7;
  const int wm = wave >> 1, wn = wave & 1;
  const int NT = Krow >> 6;

  const int sr = lane >> 3;
  const int slu = ((lane & 7) ^ sr) << 3;
  const uint16_t* aS = A  + (size_t)(m0 + wave*8 + sr) * Krow + slu;
  const uint16_t* bS = Bw + (size_t)(n0 + wave*8 + sr) * Krow + slu;

  const int l15 = lane & 15;
  const int q = lane >> 4;
  const int u0 = ((q)     ^ (l15 & 7)) << 3;
  const int u1 = ((q + 4) ^ (l15 & 7)) << 3;
  const int abase = (wm*64 + l15) << 6;     // + mi*1024
  const int bbase = (wn*64 + l15) << 6;     // + ni*1024

  facc4 acc[4][4] = {};

#define GA(bs, tt, c) gload_lds16(aS + (size_t)((c)*32)*Krow + (tt)*64, &sA[bs][((c)*32 + wave*8) << 6])
#define GB(bs, tt, c) gload_lds16(bS + (size_t)((c)*32)*Krow + (tt)*64, &sB[bs][((c)*32 + wave*8) << 6])
#define STAGE(bs, tt) do{ GA(bs,tt,0);GA(bs,tt,1);GA(bs,tt,2);GA(bs,tt,3); \
                          GB(bs,tt,0);GB(bs,tt,1);GB(bs,tt,2);GB(bs,tt,3); }while(0)

  STAGE(0, 0);
  asm volatile("s_waitcnt vmcnt(0)" ::: "memory");
  asm volatile("s_barrier" ::: "memory");
  __builtin_amdgcn_sched_barrier(0);

  #pragma unroll 1
  for (int t = 0; t < NT; ++t){
    const int c = t & 1;
    const bool st = (t + 1 < NT);
    const uint16_t* sa = sA[c];
    const uint16_t* sb = sB[c];
    if (st){ STAGE(c ^ 1, t + 1); }
    bfrag8 af[2][4], bf[2][4];
    #pragma unroll
    for (int mi = 0; mi < 4; mi++){
      af[0][mi] = *(const bfrag8*)&sa[abase + mi*1024 + u0];
      af[1][mi] = *(const bfrag8*)&sa[abase + mi*1024 + u1];
    }
    #pragma unroll
    for (int ni = 0; ni < 4; ni++){
      bf[0][ni] = *(const bfrag8*)&sb[bbase + ni*1024 + u0];
      bf[1][ni] = *(const bfrag8*)&sb[bbase + ni*1024 + u1];
    }
    __builtin_amdgcn_sched_barrier(0);
    __builtin_amdgcn_s_setprio(1);
    #pragma unroll
    for (int ks = 0; ks < 2; ks++)
      #pragma unroll
      for (int mi = 0; mi < 4; mi++)
        #pragma unroll
        for (int ni = 0; ni < 4; ni++)
          acc[mi][ni] = __builtin_amdgcn_mfma_f32_16x16x32_bf16(af[ks][mi], bf[ks][ni], acc[mi][ni], 0, 0, 0);
    __builtin_amdgcn_s_setprio(0);
    __builtin_amdgcn_sched_barrier(0);
    if (st){
      asm volatile("s_waitcnt vmcnt(0)" ::: "memory");
      asm volatile("s_barrier" ::: "memory");
      __builtin_amdgcn_sched_barrier(0);
    }
  }
#undef GA
#undef GB
#undef STAGE

  #pragma unroll
  for (int mi = 0; mi < 4; mi++)
    #pragma unroll
    for (int ni = 0; ni < 4; ni++)
      #pragma unroll
      for (int r = 0; r < 4; r++){
        const int gm = m0 + wm*64 + mi*16 + (lane >> 4)*4 + r;
        const int gn = n0 + wn*64 + ni*16 + l15;
        Cout[(size_t)gm * Ndim + gn] = acc[mi][ni][r];
      }
}

// ---------------------------------------------------------------- dt = clip(softplus(dtraw+bias)), cumsum(A*dt)
__global__ __launch_bounds__(256) void dt_cum(
    const float* __restrict__ dtraw, const float* __restrict__ A_log, const float* __restrict__ dt_bias,
    float* __restrict__ dtb, float* __restrict__ cumb, float* __restrict__ ctotb)
{
  const int g = blockIdx.x*4 + (threadIdx.x >> 6);   // (b*8+c)*64+h
  const int lane = threadIdx.x & 63;
  const int h = g & 63;
  const int r0 = (g >> 6) << 8;
  const float A = -__expf(A_log[h]);
  const float bias = dt_bias[h];
  float loc[4], s = 0.f;
  #pragma unroll
  for (int k = 0; k < 4; k++){
    const int l = lane*4 + k;
    const float xr = dtraw[(size_t)(r0 + l)*64 + h] + bias;
    const float sp = (xr > 20.f) ? xr : log1pf(__expf(xr));
    const float dt = fminf(fmaxf(sp, 1e-4f), 0.5f);
    dtb[g*256 + l] = dt;
    s += A * dt;
    loc[k] = s;
  }
  float run = s;
  #pragma unroll
  for (int off = 1; off < 64; off <<= 1){
    const float tmp = __shfl_up(run, off);
    if (lane >= off) run += tmp;
  }
  const float excl = run - s;
  #pragma unroll
  for (int k = 0; k < 4; k++) cumb[g*256 + lane*4 + k] = excl + loc[k];
  if (lane == 63) ctotb[g] = run;
}

// ---------------------------------------------------------------- pass1: per (b,c,h) conv+SiLU fused, y_intra + delta_h
__global__ __launch_bounds__(256) void chunk_pass1(
    const uint16_t* __restrict__ projb, const float* __restrict__ conv_w,
    const float* __restrict__ dtb, const float* __restrict__ cumb,
    const float* __restrict__ ctotb, uint16_t* __restrict__ yvb, float* __restrict__ dh)
{
  __shared__ __align__(16) uint16_t sCc[256*64];   // C tile, [l][n] XOR-swz
  __shared__ __align__(16) uint16_t sBc[256*64];   // B tile, [l][n] XOR-swz
  __shared__ __align__(16) uint16_t sXT[64*256];   // (xconv*dt)^T  [p][l] swz u^(p&7)^(p>>3)
  __shared__ __align__(16) uint16_t sBT[64*256];   // (B*dte)^T  [n][l] same swz
  __shared__ __align__(16) uint16_t sS[4][64*32];  // per-wave S strip [i][j] swz
  __shared__ float sCum[256];
  __shared__ float sDt[256];
  __shared__ float sDte[256];

  const int tid = threadIdx.x, lane = tid & 63, wave = tid >> 6;
  const int bx = blockIdx.x;                // ((b*8+c)*64 + h)
  const int h = bx & 63;
  const int r0 = (bx >> 6) << 8;            // global row base b*2048 + c*256

  // stage Cc/Bc via global_load_lds, source-swizzled
  {
    const int Ccol = 12288 + h*64;
    const int Bcol = 8192 + h*64;
    const int sr = lane >> 3;
    const int lu = (lane & 7) ^ (sr & 7);
    const uint16_t* cS = projb + (size_t)(r0 + wave*64 + sr)*NPAD + Ccol + lu*8;
    const uint16_t* bS = projb + (size_t)(r0 + wave*64 + sr)*NPAD + Bcol + lu*8;
    uint16_t* cD = sCc + wave*4096;
    uint16_t* bD = sBc + wave*4096;
    #pragma unroll
    for (int i = 0; i < 8; i++){
      gload_lds16(cS + (size_t)(i*8)*NPAD, cD + i*512);
      gload_lds16(bS + (size_t)(i*8)*NPAD, bD + i*512);
    }
  }
  const float ctot = ctotb[bx];
  {
    const float cv = cumb[bx*256 + tid];
    sCum[tid] = cv;
    sDt[tid]  = dtb[bx*256 + tid];
    sDte[tid] = __expf(ctot - cv);          // decay_to_end
  }
  __syncthreads();

  // reg-scatter transposed tiles; x comes from fused depthwise conv(4)+SiLU
  {
    const int lsub = tid >> 3;              // 0..31
    const int p0 = (tid & 7) * 8;
    float wc[8][4];
    #pragma unroll
    for (int k = 0; k < 8; k++){
      const float4 ww = *(const float4*)(conv_w + (size_t)(h*64 + p0 + k)*4);
      wc[k][0]=ww.x; wc[k][1]=ww.y; wc[k][2]=ww.z; wc[k][3]=ww.w;
    }
    #pragma unroll
    for (int rep = 0; rep < 8; rep++){
      const int l = rep*32 + lsub;
      const float dtl = sDt[l];
      const float dte = sDte[l];
      // depthwise conv over global-time within batch
      float ca[8] = {0,0,0,0,0,0,0,0};
      const int tb = (r0 & 2047) + l;       // t within batch
      #pragma unroll
      for (int j = 0; j < 4; j++){
        if (tb - 3 + j >= 0){
          const bfrag8 px = *(const bfrag8*)(projb + (size_t)(r0 + l - 3 + j)*NPAD + DI + h*64 + p0);
          #pragma unroll
          for (int k = 0; k < 8; k++) ca[k] += b2f((uint16_t)px[k]) * wc[k][j];
        }
      }
      const bfrag8 vb = *(const bfrag8*)(projb + (size_t)(r0 + l)*NPAD + 8192 + h*64 + p0);
      const int usrc = l >> 3;
      const int lrem = l & 7;
      #pragma unroll
      for (int k = 0; k < 8; k++){
        const int p = p0 + k;
        const int phys = usrc ^ (p & 7) ^ (p >> 3);
        const float xv = ca[k] / (1.f + __expf(-ca[k]));   // SiLU
        sXT[p*256 + phys*8 + lrem] = f2b(xv * dtl);
        sBT[p*256 + phys*8 + lrem] = f2b(b2f((uint16_t)vb[k]) * dte);
      }
    }
  }
  __syncthreads();

  const int i0 = wave * 64;                 // this wave's i-strip
  facc4 yacc[4][4] = {};

  #pragma unroll 1
  for (int jt = 0; jt < 8; jt++){
    // S'[j,i] = B @ C^T  (swapped so repack is contiguous b64 writes)
    facc4 sacc[2][4] = {};
    #pragma unroll
    for (int ks = 0; ks < 2; ks++){
      bfrag8 aB[2], bC[4];
      #pragma unroll
      for (int jf = 0; jf < 2; jf++){
        const int j = jt*32 + jf*16 + (lane & 15);
        const int u = ks*4 + (lane >> 4);
        aB[jf] = *(const bfrag8*)(sBc + j*64 + ((u ^ (j & 7)) << 3));
      }
      #pragma unroll
      for (int f = 0; f < 4; f++){
        const int i = i0 + f*16 + (lane & 15);
        const int u = ks*4 + (lane >> 4);
        bC[f] = *(const bfrag8*)(sCc + i*64 + ((u ^ (i & 7)) << 3));
      }
      #pragma unroll
      for (int jf = 0; jf < 2; jf++)
        #pragma unroll
        for (int f = 0; f < 4; f++)
          sacc[jf][f] = __builtin_amdgcn_mfma_f32_16x16x32_bf16(aB[jf], bC[f], sacc[jf][f], 0, 0, 0);
    }
    // decay*SCALE, causal mask, pack bf16 -> per-wave S strip [i][j]
    #pragma unroll
    for (int jf = 0; jf < 2; jf++)
      #pragma unroll
      for (int f = 0; f < 4; f++){
        const int iloc = f*16 + (lane & 15);
        const float cumi = sCum[i0 + iloc];
        uint64_t pk = 0;
        #pragma unroll
        for (int r = 0; r < 4; r++){
          const int j = jt*32 + jf*16 + (lane >> 4)*4 + r;
          float v = 0.f;
          if (j <= i0 + iloc)
            v = sacc[jf][f][r] * SCALEF * __expf(cumi - sCum[j]);
          pk |= ((uint64_t)f2b(v)) << (16*r);
        }
        const int jl = jf*16 + (lane >> 4)*4;
        const int phys2 = (jl >> 3) ^ (iloc & 3);
        *(uint64_t*)(&sS[wave][iloc*32 + phys2*8 + (jl & 7)]) = pk;
      }
    // y_intra += S_strip @ xdt   (A from strip, B from sXT)
    bfrag8 bX[4];
    #pragma unroll
    for (int pf = 0; pf < 4; pf++){
      const int p = pf*16 + (lane & 15);
      const int u = jt*4 + (lane >> 4);
      bX[pf] = *(const bfrag8*)(sXT + p*256 + ((u ^ (p & 7) ^ (p >> 3)) << 3));
    }
    #pragma unroll
    for (int f = 0; f < 4; f++){
      const int iloc = f*16 + (lane & 15);
      const int phys2 = (lane >> 4) ^ (iloc & 3);
      const bfrag8 aS = *(const bfrag8*)(&sS[wave][iloc*32 + phys2*8]);
      #pragma unroll
      for (int pf = 0; pf < 4; pf++)
        yacc[f][pf] = __builtin_amdgcn_mfma_f32_16x16x32_bf16(aS, bX[pf], yacc[f][pf], 0, 0, 0);
    }
  }

  // delta_h[p,n] = sum_l (xconv*dt)[l,p] * (B*dte)[l,n]; wave owns p-strip wave*16
  facc4 dacc[4] = {};
  #pragma unroll
  for (int ks = 0; ks < 8; ks++){
    const int p = wave*16 + (lane & 15);
    const int u = ks*4 + (lane >> 4);
    const bfrag8 aX = *(const bfrag8*)(sXT + p*256 + ((u ^ (p & 7) ^ (p >> 3)) << 3));
    #pragma unroll
    for (int nf = 0; nf < 4; nf++){
      const int n = nf*16 + (lane & 15);
      const bfrag8 bB = *(const bfrag8*)(sBT + n*256 + ((u ^ (n & 7) ^ (n >> 3)) << 3));
      dacc[nf] = __builtin_amdgcn_mfma_f32_16x16x32_bf16(aX, bB, dacc[nf], 0, 0, 0);
    }
  }

  #pragma unroll
  for (int f = 0; f < 4; f++)
    #pragma unroll
    for (int pf = 0; pf < 4; pf++)
      #pragma unroll
      for (int r = 0; r < 4; r++){
        const int i = i0 + f*16 + (lane >> 4)*4 + r;
        const int p = pf*16 + (lane & 15);
        yvb[(size_t)(r0 + i)*DI + h*64 + p] = f2b(yacc[f][pf][r]);
      }
  #pragma unroll
  for (int nf = 0; nf < 4; nf++)
    #pragma unroll
    for (int r = 0; r < 4; r++){
      const int p = wave*16 + (lane >> 4)*4 + r;
      const int n = nf*16 + (lane & 15);
      dh[(size_t)bx*4096 + p*64 + n] = dacc[nf][r];
    }
}

// ---------------------------------------------------------------- cross-chunk state scan (8 steps)
__global__ __launch_bounds__(256) void scan_states(
    const float* __restrict__ dh, const float* __restrict__ ctotb, float* __restrict__ states)
{
  const int bh = blockIdx.x;                // b*64 + h
  const int b = bh >> 6, h = bh & 63;
  const int tid = threadIdx.x;
  float st[16];
  #pragma unroll
  for (int k = 0; k < 16; k++) st[k] = 0.f;
  for (int c = 0; c < 8; c++){
    const int g = (b*8 + c)*64 + h;
    const size_t base = (size_t)g * 4096;
    const float cd = __expf(ctotb[g]);
    #pragma unroll
    for (int k = 0; k < 4; k++){
      const int e = tid*4 + k*1024;
      float4 o; o.x = st[k*4]; o.y = st[k*4+1]; o.z = st[k*4+2]; o.w = st[k*4+3];
      *(float4*)(states + base + e) = o;    // state BEFORE chunk c
      const float4 d = *(const float4*)(dh + base + e);
      st[k*4]   = cd*st[k*4]   + d.x;
      st[k*4+1] = cd*st[k*4+1] + d.y;
      st[k*4+2] = cd*st[k*4+2] + d.z;
      st[k*4+3] = cd*st[k*4+3] + d.w;
    }
  }
}

// ---------------------------------------------------------------- pass2: y += exp(cum)*SCALE * C @ h^T  (bf16 RMW)
__global__ __launch_bounds__(256) void chunk_pass2(
    const uint16_t* __restrict__ projb, const float* __restrict__ states,
    const float* __restrict__ cumb, uint16_t* __restrict__ yvb)
{
  __shared__ __align__(16) uint16_t sCc[256*64];
  __shared__ __align__(16) uint16_t sH[64*64];    // [p][n] swz
  __shared__ float sCum[256];
  const int tid = threadIdx.x, lane = tid & 63, wave = tid >> 6;
  const int bx = blockIdx.x, h = bx & 63, r0 = (bx >> 6) << 8;
  {
    const int Ccol = 12288 + h*64;
    const int sr = lane >> 3;
    const int lu = (lane & 7) ^ (sr & 7);
    const uint16_t* cS = projb + (size_t)(r0 + wave*64 + sr)*NPAD + Ccol + lu*8;
    uint16_t* cD = sCc + wave*4096;
    #pragma unroll
    for (int i = 0; i < 8; i++) gload_lds16(cS + (size_t)(i*8)*NPAD, cD + i*512);
  }
  #pragma unroll
  for (int k = 0; k < 4; k++){
    const int e = tid*4 + k*1024;
    const float4 v = *(const float4*)(states + (size_t)bx*4096 + e);
    const int p = e >> 6, n0 = e & 63;
    const int phys = (n0 >> 3) ^ (p & 7);
    uint64_t pk = (uint64_t)f2b(v.x) | ((uint64_t)f2b(v.y) << 16)
                | ((uint64_t)f2b(v.z) << 32) | ((uint64_t)f2b(v.w) << 48);
    *(uint64_t*)(&sH[p*64 + phys*8 + (n0 & 7)]) = pk;
  }
  sCum[tid] = cumb[bx*256 + tid];
  __syncthreads();

  const int i0 = wave*64;
  facc4 acc[4][4] = {};
  #pragma unroll
  for (int ks = 0; ks < 2; ks++){
    bfrag8 aC[4], bH[4];
    #pragma unroll
    for (int f = 0; f < 4; f++){
      const int i = i0 + f*16 + (lane & 15);
      const int u = ks*4 + (lane >> 4);
      aC[f] = *(const bfrag8*)(sCc + i*64 + ((u ^ (i & 7)) << 3));
    }
    #pragma unroll
    for (int pf = 0; pf < 4; pf++){
      const int p = pf*16 + (lane & 15);
      const int u = ks*4 + (lane >> 4);
      bH[pf] = *(const bfrag8*)(sH + p*64 + ((u ^ (p & 7)) << 3));
    }
    #pragma unroll
    for (int f = 0; f < 4; f++)
      #pragma unroll
      for (int pf = 0; pf < 4; pf++)
        acc[f][pf] = __builtin_amdgcn_mfma_f32_16x16x32_bf16(aC[f], bH[pf], acc[f][pf], 0, 0, 0);
  }
  #pragma unroll
  for (int f = 0; f < 4; f++)
    #pragma unroll
    for (int r = 0; r < 4; r++){
      const int i = i0 + f*16 + (lane >> 4)*4 + r;
      const float sc = SCALEF * __expf(sCum[i]);
      #pragma unroll
      for (int pf = 0; pf < 4; pf++){
        const int p = pf*16 + (lane & 15);
        uint16_t* yp = yvb + (size_t)(r0 + i)*DI + h*64 + p;
        *yp = f2b(b2f(*yp) + acc[f][pf][r] * sc);
      }
    }
}

// ---------------------------------------------------------------- RMSNorm + SiLU(z) gate -> bf16
__global__ __launch_bounds__(256) void norm_gate(
    const uint16_t* __restrict__ yvb, const uint16_t* __restrict__ projb, uint16_t* __restrict__ yb)
{
  const int row = blockIdx.x, tid = threadIdx.x;
  float v[16];
  float ss = 0.f;
  #pragma unroll
  for (int k = 0; k < 2; k++){
    const bfrag8 y8 = *(const bfrag8*)(yvb + (size_t)row*DI + tid*8 + k*2048);
    #pragma unroll
    for (int j = 0; j < 8; j++){
      const float f = b2f((uint16_t)y8[j]);
      v[k*8+j] = f;
      ss += f*f;
    }
  }
  #pragma unroll
  for (int off = 32; off > 0; off >>= 1) ss += __shfl_down(ss, off);
  __shared__ float red[4];
  if ((tid & 63) == 0) red[tid >> 6] = ss;
  __syncthreads();
  const float inv = rsqrtf((red[0]+red[1]+red[2]+red[3]) * (1.f/4096.f) + 1.1920929e-07f);
  #pragma unroll
  for (int k = 0; k < 2; k++){
    const int e = tid*8 + k*2048;
    const bfrag8 z8 = *(const bfrag8*)(projb + (size_t)row*NPAD + e);
    uint16_t o[8];
    #pragma unroll
    for (int j = 0; j < 8; j++){
      const float z = b2f((uint16_t)z8[j]);
      const float g = z / (1.f + __expf(-z));
      o[j] = f2b(v[k*8+j] * inv * g);
    }
    uint4 pk;
    pk.x = (uint32_t)o[0] | ((uint32_t)o[1] << 16);
    pk.y = (uint32_t)o[2] | ((uint32_t)o[3] << 16);
    pk.z = (uint32_t)o[4] | ((uint32_t)o[5] << 16);
    pk.w = (uint32_t)o[6] | ((uint32_t)o[7] << 16);
    *(uint4*)(yb + (size_t)row*DI + e) = pk;
  }
}

// ---------------------------------------------------------------- launcher
extern "C" void kernel_launch(void* const* d_in, const int* in_sizes, int n_in,
                              void* d_out, int out_size, void* d_ws, size_t ws_size,
                              hipStream_t stream)
{
  (void)in_sizes; (void)n_in; (void)out_size; (void)ws_size;
  const float* x         = (const float*)d_in[0];
  const float* in_proj_w = (const float*)d_in[1];
  const float* conv_w    = (const float*)d_in[2];
  const float* A_log     = (const float*)d_in[3];
  const float* dt_bias   = (const float*)d_in[4];
  const float* out_proj_w= (const float*)d_in[5];
  float* out = (float*)d_out;

  char* ws = (char*)d_ws;
  uint16_t* xb    = (uint16_t*)(ws + 0);               // 4096x2048 bf16 = 16.8MB (dead after gemms)
  uint16_t* yvb   = (uint16_t*)(ws + 0);               // 4096x4096 bf16 = 33.5MB (overlaps xb + wb head)
  uint16_t* wb    = (uint16_t*)(ws + 16777216);        // 16448x2048 bf16 -> end 84,148,224 (dead after gemms)
  uint16_t* projb = (uint16_t*)(ws + 84148224);        // 4096x16384 bf16 -> end 218,365,952
  float* dtraw    = (float*)(ws + 218365952);          // 4096x64 f32 -> 219,414,528
  float* dtb      = (float*)(ws + 219414528);          // 1024x256 f32
  float* cumb     = (float*)(ws + 220463104);          // 1024x256 f32
  float* ctotb    = (float*)(ws + 221511680);          // 1024 f32
  uint16_t* yb    = (uint16_t*)(ws + 221515776);       // 4096x4096 bf16 -> 255,070,208
  float* dh       = (float*)(ws + 255070208);          // 1024x64x64 f32 -> 271,847,424
  float* states   = (float*)(ws + 271847424);          // 1024x64x64 f32 -> 288,624,640
  uint16_t* opb   = (uint16_t*)(ws + 288624640);       // 2048x4096 bf16 -> 305,401,856

  // fused casts (x, in_proj_w incl dt rows, out_proj_w)
  cast3<<<49280, 256, 0, stream>>>(x, in_proj_w, out_proj_w, xb, wb, opb);

  // in_proj GEMM (bf16 out, cols 0..16384): 16 panels x 64 blocks = 1024 = 4 exact generations
  gemm_bt5<<<1024, 512, 0, stream>>>(xb, wb, projb);
  // dt GEMM (f32 out): 128 blocks, rows of W [16384,16448)
  gemm_dt<<<128, 256, 0, stream>>>(xb, wb + (size_t)16384*2048, dtraw);

  dt_cum<<<256, 256, 0, stream>>>(dtraw, A_log, dt_bias, dtb, cumb, ctotb);
  chunk_pass1<<<1024, 256, 0, stream>>>(projb, conv_w, dtb, cumb, ctotb, yvb, dh);
  scan_states<<<128, 256, 0, stream>>>(dh, ctotb, states);
  chunk_pass2<<<1024, 256, 0, stream>>>(projb, states, cumb, yvb);
  norm_gate<<<4096, 256, 0, stream>>>(yvb, projb, yb);

  // out_proj GEMM: 128x128 tiles, XCD-square map, 512 blocks, 2/CU, f32 out
  gemm97<<<512, 256, 0, stream>>>(yb, opb, out, 2048, 4096);
}